// Round 13
// baseline (3150.736 us; speedup 1.0000x reference)
//
#include <hip/hip_runtime.h>
#include <stdint.h>

typedef unsigned short u16;
typedef _Float16 f16;
typedef f16 f16x8 __attribute__((ext_vector_type(8)));
typedef float f32x4 __attribute__((ext_vector_type(4)));
typedef unsigned short u16x4 __attribute__((ext_vector_type(4)));
typedef unsigned short u16x8 __attribute__((ext_vector_type(8)));

#define MFMA16(a, b, c) __builtin_amdgcn_mfma_f32_16x16x32_f16(a, b, c, 0, 0, 0)

__device__ __forceinline__ u16 f2h_u(float f) {
  union { f16 h; u16 u; } v; v.h = (f16)f; return v.u;
}
__device__ __forceinline__ float h2f(u16 u) {
  union { u16 u; f16 h; } v; v.u = u; return (float)v.h;
}
__device__ __forceinline__ f16x8 ld_h8(const u16* p) {
  return *(const f16x8*)p;
}
// async global->LDS, 16B per lane; LDS dest = wave-uniform base + lane*16
__device__ __forceinline__ void gl_lds16(const u16* g, u16* l) {
  __builtin_amdgcn_global_load_lds(
      (const __attribute__((address_space(1))) void*)g,
      (__attribute__((address_space(3))) void*)l, 16, 0, 0);
}

// ---------------------------------------------------------------------------
// f32 -> f16 elementwise convert (n8 = n/8 groups of 8)
// ---------------------------------------------------------------------------
__global__ __launch_bounds__(256) void convert_f32_f16(
    const float* __restrict__ in, u16* __restrict__ out, int n8)
{
  int i = blockIdx.x * 256 + threadIdx.x;
  int stride = gridDim.x * 256;
  for (; i < n8; i += stride) {
    f32x4 a = *(const f32x4*)(in + (size_t)i * 8);
    f32x4 b = *(const f32x4*)(in + (size_t)i * 8 + 4);
    u16x8 o;
#pragma unroll
    for (int j = 0; j < 4; ++j) { o[j] = f2h_u(a[j]); o[4 + j] = f2h_u(b[j]); }
    *(u16x8*)(out + (size_t)i * 8) = o;
  }
}

// ---------------------------------------------------------------------------
// f16-bits transpose (for V^T). Grid: (C/64, R/64, Z).
// ---------------------------------------------------------------------------
__global__ __launch_bounds__(256) void transpose_h16(
    const u16* __restrict__ in, u16* __restrict__ out,
    int R, int C, int ldi, int ldo, long zin, long zout)
{
  __shared__ u16 tile[64 * 66];
  const u16* ip = in + (size_t)blockIdx.z * zin;
  u16* op = out + (size_t)blockIdx.z * zout;
  int x0 = blockIdx.x * 64, y0 = blockIdx.y * 64;
  int t = threadIdx.x;
  int xr = (t & 15) * 4;
  int yr = t >> 4;
#pragma unroll
  for (int p = 0; p < 4; ++p) {
    int y = yr + p * 16;
    u16x4 v = *(const u16x4*)(ip + (size_t)(y0 + y) * ldi + x0 + xr);
    tile[y * 66 + xr + 0] = v.x;
    tile[y * 66 + xr + 1] = v.y;
    tile[y * 66 + xr + 2] = v.z;
    tile[y * 66 + xr + 3] = v.w;
  }
  __syncthreads();
#pragma unroll
  for (int p = 0; p < 4; ++p) {
    int x = (t >> 4) + p * 16;
    int yq = (t & 15) * 4;
    u16x4 v;
    v.x = tile[(yq + 0) * 66 + x];
    v.y = tile[(yq + 1) * 66 + x];
    v.z = tile[(yq + 2) * 66 + x];
    v.w = tile[(yq + 3) * 66 + x];
    *(u16x4*)(op + (size_t)(x0 + x) * ldo + y0 + yq) = v;
  }
}

// ---------------------------------------------------------------------------
// GEMM v7 (fused weight transpose, depth-2 B pipeline):
// C[M][N] = A[M][K](f16) * W[K][N](f32). 256x128 tile, 8 waves, BK=32,
// 3 LDS buffers. A via gl_lds16 (src-XOR-swizzled); B reg-staged depth-2:
// two named reg sets bw0/bw1 (manually 2x-unrolled K-loop -> compile-time
// parity), BLOAD(t+2) at iter top, steady-state vmcnt(10)
// (= leave [B(t+2) x8, A(t+2) x2] in flight), BWRITE(t+1) after the wait,
// lgkmcnt(0) + one barrier/iter. REQUIRES nk EVEN.
// Grid: (N/128, M/256, nz); split-K via blockIdx.z.
// ---------------------------------------------------------------------------
template <bool F32OUT>
__global__ __launch_bounds__(512, 4) void gemm_ktn(
    const u16* __restrict__ A, const float* __restrict__ W, void* __restrict__ Cv,
    int Ksp, int lda, int ldw, int ldc, long zstride)
{
  __shared__ alignas(16) u16 As[3 * 256 * 32];   // 3 x 16 KB
  __shared__ alignas(16) u16 Bs[3 * 128 * 32];   // 3 x  8 KB
  int tid = threadIdx.x;
  int lane = tid & 63;
  int wave = tid >> 6;
  int wm = wave >> 2, wn = wave & 3;
  int r15 = lane & 15, g = lane >> 4;

  // XCD-bijective swizzle + column-major (M fastest) decomposition
  int gx = gridDim.x, gy = gridDim.y;
  int nwg = gx * gy;
  int flat = blockIdx.y * gx + blockIdx.x;
  int q = nwg >> 3, rr = nwg & 7, xcd = flat & 7, lo = flat >> 3;
  int s = ((xcd < rr) ? xcd * (q + 1) : rr * (q + 1) + (xcd - rr) * q) + lo;
  int by = s % gy;
  int bx = s / gy;
  int row0 = by * 256, col0 = bx * 128;
  int kbeg = blockIdx.z * Ksp;

  // A staging: lane covers LDS row tid>>2, 16B chunk tid&3, src XOR-swizzled
  int rA = tid >> 2;
  int pc = tid & 3;
  int cs = pc ^ ((rA >> 1) & 3);
  const u16* Ag0 = A + (size_t)(row0 + rA) * lda + kbeg + cs * 8;  // rows 0..127
  const u16* Ag1 = Ag0 + (size_t)128 * lda;                        // rows 128..255

  // B staging: col cB (coalesced across lanes), k-chunk kc (8 k each)
  int cB = tid & 127;
  int kc = tid >> 7;
  const float* Wg = W + (size_t)(kbeg + kc * 8) * ldw + col0 + cB;
  int bwoff = cB * 32 + ((kc ^ ((cB >> 1) & 3)) * 8);  // u16 units

  f32x4 acc[8][2];
#pragma unroll
  for (int i = 0; i < 8; ++i)
#pragma unroll
    for (int j = 0; j < 2; ++j) acc[i][j] = (f32x4){0.f, 0.f, 0.f, 0.f};

  int nk = Ksp >> 5;       // MUST be even
  float bw0[8], bw1[8];

  auto STAGE_A = [&](int kk, int b) {
    u16* la = As + b * 8192 + wave * 512;
    gl_lds16(Ag0 + (size_t)kk * 32, la);
    gl_lds16(Ag1 + (size_t)kk * 32, la + 4096);
  };
  int swz = (g ^ ((r15 >> 1) & 3)) * 8;

#define BLOAD0(kk) { _Pragma("unroll") for (int j = 0; j < 8; ++j) bw0[j] = Wg[(size_t)((kk) * 32 + j) * ldw]; }
#define BLOAD1(kk) { _Pragma("unroll") for (int j = 0; j < 8; ++j) bw1[j] = Wg[(size_t)((kk) * 32 + j) * ldw]; }
#define BWRITE0(b) { u16x8 o; _Pragma("unroll") for (int j = 0; j < 8; ++j) o[j] = f2h_u(bw0[j]); *(u16x8*)(Bs + (b) * 4096 + bwoff) = o; }
#define BWRITE1(b) { u16x8 o; _Pragma("unroll") for (int j = 0; j < 8; ++j) o[j] = f2h_u(bw1[j]); *(u16x8*)(Bs + (b) * 4096 + bwoff) = o; }

  // prologue: B0->bw0, B1->bw1, A0, A1 (queue=20); vmcnt(2) confirms B0,B1,A0
  BLOAD0(0);
  BLOAD1(1);
  STAGE_A(0, 0);
  STAGE_A(1, 1);
  asm volatile("s_waitcnt vmcnt(2)" ::: "memory");
  BWRITE0(0);
  asm volatile("s_waitcnt lgkmcnt(0)" ::: "memory");
  __builtin_amdgcn_s_barrier();

  int b0 = 0;
  for (int k = 0; k < nk; k += 2) {
    // ================= half A: tile t = k (even; B(t+2) -> bw0) =============
    {
      const int t = k;
      const u16* Ab = As + b0 * 8192;
      const u16* Bb = Bs + b0 * 4096;
      if (t + 2 < nk) {
        BLOAD0(t + 2);
        int b2 = b0 + 2; if (b2 >= 3) b2 -= 3;
        STAGE_A(t + 2, b2);
      }
      f16x8 bfr[2], af[4];
#pragma unroll
      for (int ni = 0; ni < 2; ++ni)
        bfr[ni] = ld_h8(Bb + (wn * 32 + ni * 16 + r15) * 32 + swz);
#pragma unroll
      for (int m2 = 0; m2 < 4; ++m2)
        af[m2] = ld_h8(Ab + (wm * 128 + m2 * 16 + r15) * 32 + swz);
      __builtin_amdgcn_s_setprio(1);
#pragma unroll
      for (int m2 = 0; m2 < 4; ++m2)
#pragma unroll
        for (int ni = 0; ni < 2; ++ni)
          acc[m2][ni] = MFMA16(af[m2], bfr[ni], acc[m2][ni]);
      f16x8 ag[4];
#pragma unroll
      for (int m2 = 0; m2 < 4; ++m2)
        ag[m2] = ld_h8(Ab + (wm * 128 + (4 + m2) * 16 + r15) * 32 + swz);
#pragma unroll
      for (int m2 = 0; m2 < 4; ++m2)
#pragma unroll
        for (int ni = 0; ni < 2; ++ni)
          acc[4 + m2][ni] = MFMA16(ag[m2], bfr[ni], acc[4 + m2][ni]);
      __builtin_amdgcn_s_setprio(0);
      // confirm B(t+1)+A(t+1); leave [B(t+2)x8, A(t+2)x2]; B(t+1) is bw1
      if (t + 2 < nk) {
        asm volatile("s_waitcnt vmcnt(10)" ::: "memory");
      } else {
        asm volatile("s_waitcnt vmcnt(0)" ::: "memory");
      }
      int b1 = b0 + 1; if (b1 >= 3) b1 -= 3;
      BWRITE1(b1);      // t+1 < nk always here (nk even, t <= nk-2)
      asm volatile("s_waitcnt lgkmcnt(0)" ::: "memory");
      __builtin_amdgcn_s_barrier();
      b0 = (b0 == 2) ? 0 : b0 + 1;
    }
    // ================= half B: tile t = k+1 (odd; B(t+2) -> bw1) ============
    {
      const int t = k + 1;
      const u16* Ab = As + b0 * 8192;
      const u16* Bb = Bs + b0 * 4096;
      if (t + 2 < nk) {
        BLOAD1(t + 2);
        int b2 = b0 + 2; if (b2 >= 3) b2 -= 3;
        STAGE_A(t + 2, b2);
      }
      f16x8 bfr[2], af[4];
#pragma unroll
      for (int ni = 0; ni < 2; ++ni)
        bfr[ni] = ld_h8(Bb + (wn * 32 + ni * 16 + r15) * 32 + swz);
#pragma unroll
      for (int m2 = 0; m2 < 4; ++m2)
        af[m2] = ld_h8(Ab + (wm * 128 + m2 * 16 + r15) * 32 + swz);
      __builtin_amdgcn_s_setprio(1);
#pragma unroll
      for (int m2 = 0; m2 < 4; ++m2)
#pragma unroll
        for (int ni = 0; ni < 2; ++ni)
          acc[m2][ni] = MFMA16(af[m2], bfr[ni], acc[m2][ni]);
      f16x8 ag[4];
#pragma unroll
      for (int m2 = 0; m2 < 4; ++m2)
        ag[m2] = ld_h8(Ab + (wm * 128 + (4 + m2) * 16 + r15) * 32 + swz);
#pragma unroll
      for (int m2 = 0; m2 < 4; ++m2)
#pragma unroll
        for (int ni = 0; ni < 2; ++ni)
          acc[4 + m2][ni] = MFMA16(ag[m2], bfr[ni], acc[4 + m2][ni]);
      __builtin_amdgcn_s_setprio(0);
      if (t + 1 < nk) {
        if (t + 2 < nk) {
          asm volatile("s_waitcnt vmcnt(10)" ::: "memory");
        } else {
          asm volatile("s_waitcnt vmcnt(0)" ::: "memory");
        }
        int b1 = b0 + 1; if (b1 >= 3) b1 -= 3;
        BWRITE0(b1);    // B(t+1) is bw0
      } else {
        asm volatile("s_waitcnt vmcnt(0)" ::: "memory");
      }
      asm volatile("s_waitcnt lgkmcnt(0)" ::: "memory");
      __builtin_amdgcn_s_barrier();
      b0 = (b0 == 2) ? 0 : b0 + 1;
    }
  }
#undef BLOAD0
#undef BLOAD1
#undef BWRITE0
#undef BWRITE1

  // C/D layout: col = lane&15, row = (lane>>4)*4 + reg
#pragma unroll
  for (int mi = 0; mi < 8; ++mi)
#pragma unroll
    for (int ni = 0; ni < 2; ++ni) {
      int row = row0 + wm * 128 + mi * 16 + g * 4;
      int col = col0 + wn * 32 + ni * 16 + r15;
#pragma unroll
      for (int r = 0; r < 4; ++r) {
        if constexpr (F32OUT)
          ((float*)Cv)[(size_t)blockIdx.z * zstride + (size_t)(row + r) * ldc + col] = acc[mi][ni][r];
        else
          ((u16*)Cv)[(size_t)blockIdx.z * zstride + (size_t)(row + r) * ldc + col] = f2h_u(acc[mi][ni][r]);
      }
    }
}

// ---------------------------------------------------------------------------
// out[i] = p[i] + p[half + i]   (f32, vectorized x4; n4 = n/4)
// ---------------------------------------------------------------------------
__global__ __launch_bounds__(256) void reduce_add2_f32(
    const float* __restrict__ p, float* __restrict__ out, int n4, long half)
{
  int i = blockIdx.x * 256 + threadIdx.x;
  int stride = gridDim.x * 256;
  for (; i < n4; i += stride) {
    f32x4 a = *(const f32x4*)(p + (size_t)i * 4);
    f32x4 b = *(const f32x4*)(p + half + (size_t)i * 4);
    *(f32x4*)(out + (size_t)i * 4) = a + b;
  }
}

// ---------------------------------------------------------------------------
// out_f16[i] = sum of 4 f32 partial slices (n4 = n/4 groups of 4)
// ---------------------------------------------------------------------------
__global__ __launch_bounds__(256) void reduce_add4_f16(
    const float* __restrict__ p, u16* __restrict__ out, int n4, long zs)
{
  int i = blockIdx.x * 256 + threadIdx.x;
  int stride = gridDim.x * 256;
  for (; i < n4; i += stride) {
    f32x4 a = *(const f32x4*)(p + (size_t)i * 4);
    a += *(const f32x4*)(p + zs + (size_t)i * 4);
    a += *(const f32x4*)(p + 2 * zs + (size_t)i * 4);
    a += *(const f32x4*)(p + 3 * zs + (size_t)i * 4);
    u16x4 o;
#pragma unroll
    for (int j = 0; j < 4; ++j) o[j] = f2h_u(a[j]);
    *(u16x4*)(out + (size_t)i * 4) = o;
  }
}

// ---------------------------------------------------------------------------
// Per-(t, head) RMSNorm(*w) + RoPE for Q (f16 in place; w, freqs f32).
// ---------------------------------------------------------------------------
__global__ __launch_bounds__(64) void norm_rope_q(
    u16* __restrict__ q, const float* __restrict__ w,
    const float* __restrict__ fc, const float* __restrict__ fs)
{
  int t = blockIdx.x, h = blockIdx.y, lane = threadIdx.x;
  u16* row = q + (size_t)t * 16384 + h * 512;
  u16x8 v = *(const u16x8*)(row + lane * 8);
  float x[8];
  float ss = 0.f;
#pragma unroll
  for (int j = 0; j < 8; ++j) { x[j] = h2f(v[j]); ss += x[j] * x[j]; }
#pragma unroll
  for (int m = 1; m < 64; m <<= 1) ss += __shfl_xor(ss, m, 64);
  float rms = rsqrtf(ss * (1.f / 512.f) + 1e-6f);
  f32x4 w0 = *(const f32x4*)(w + lane * 8);
  f32x4 w1 = *(const f32x4*)(w + lane * 8 + 4);
  float y[8];
#pragma unroll
  for (int j = 0; j < 4; ++j) {
    y[j] = x[j] * rms * w0[j];
    y[4 + j] = x[4 + j] * rms * w1[j];
  }
  if (lane < 16) {
    f32x4 cv = *(const f32x4*)(fc + t * 64 + lane * 4);
    f32x4 sv = *(const f32x4*)(fs + t * 64 + lane * 4);
#pragma unroll
    for (int j = 0; j < 4; ++j) {
      float c = cv[j], s = sv[j];
      float a = y[2 * j], b = y[2 * j + 1];
      y[2 * j] = a * c - b * s;
      y[2 * j + 1] = a * s + b * c;
    }
  }
  u16x8 o;
#pragma unroll
  for (int j = 0; j < 8; ++j) o[j] = f2h_u(y[j]);
  *(u16x8*)(row + lane * 8) = o;
}

// ---------------------------------------------------------------------------
// Per-(t, kv): shared sumsq; k = rms*k_w + RoPE (in place), v = rms (-> vout).
// ---------------------------------------------------------------------------
__global__ __launch_bounds__(64) void norm_kv(
    u16* __restrict__ kraw, u16* __restrict__ vout, const float* __restrict__ kw,
    const float* __restrict__ fc, const float* __restrict__ fs)
{
  int t = blockIdx.x, kv = blockIdx.y, lane = threadIdx.x;
  u16* row  = kraw + (size_t)t * 2048 + kv * 512;
  u16* vrow = vout + (size_t)t * 2048 + kv * 512;
  u16x8 v = *(const u16x8*)(row + lane * 8);
  float x[8];
  float ss = 0.f;
#pragma unroll
  for (int j = 0; j < 8; ++j) { x[j] = h2f(v[j]); ss += x[j] * x[j]; }
#pragma unroll
  for (int m = 1; m < 64; m <<= 1) ss += __shfl_xor(ss, m, 64);
  float rms = rsqrtf(ss * (1.f / 512.f) + 1e-6f);
  f32x4 w0 = *(const f32x4*)(kw + lane * 8);
  f32x4 w1 = *(const f32x4*)(kw + lane * 8 + 4);
  float yk[8], yv[8];
#pragma unroll
  for (int j = 0; j < 4; ++j) {
    yv[j] = x[j] * rms;           yv[4 + j] = x[4 + j] * rms;
    yk[j] = yv[j] * w0[j];        yk[4 + j] = yv[4 + j] * w1[j];
  }
  if (lane < 16) {
    f32x4 cv = *(const f32x4*)(fc + t * 64 + lane * 4);
    f32x4 sv = *(const f32x4*)(fs + t * 64 + lane * 4);
#pragma unroll
    for (int j = 0; j < 4; ++j) {
      float c = cv[j], s = sv[j];
      float a = yk[2 * j], b = yk[2 * j + 1];
      yk[2 * j] = a * c - b * s;
      yk[2 * j + 1] = a * s + b * c;
    }
  }
  u16x8 ok, ov;
#pragma unroll
  for (int j = 0; j < 8; ++j) { ok[j] = f2h_u(yk[j]); ov[j] = f2h_u(yv[j]); }
  *(u16x8*)(row + lane * 8) = ok;
  *(u16x8*)(vrow + lane * 8) = ov;
}

// ---------------------------------------------------------------------------
// Flash attention v2: 4-wave block, 32 q-rows, D=512 split 4x128 across waves.
// ---------------------------------------------------------------------------
__global__ __launch_bounds__(256) void attn2_kernel(
    const u16* __restrict__ Q, const u16* __restrict__ Kb,
    const u16* __restrict__ Vt, u16* __restrict__ Y)
{
  __shared__ float Sred[4 * 32 * 68];
  __shared__ u16 Plds[32 * 64];
  __shared__ float scf[32];
  __shared__ float linv[32];
  __shared__ int nf[4];

  int h = blockIdx.x;
  int qtb = 31 - blockIdx.y;
  int kv = h >> 3;
  int tid = threadIdx.x;
  int lane = tid & 63;
  int w = tid >> 6;
  int r15 = lane & 15, g = lane >> 4;
  int qbase = qtb * 32;
  int dbase = w * 128;

  int jloc = lane >> 3, cl = lane & 7;
  int jrow = w * 8 + jloc;
  int qr_sm = qbase + jrow;

  f16x8 qf[2][4];
  {
    const u16* qp = Q + (size_t)(qbase + r15) * 16384 + h * 512 + dbase + g * 8;
#pragma unroll
    for (int mi = 0; mi < 2; ++mi)
#pragma unroll
      for (int ks = 0; ks < 4; ++ks)
        qf[mi][ks] = ld_h8(qp + (size_t)mi * 16 * 16384 + ks * 32);
  }

  f32x4 acc[2][8];
#pragma unroll
  for (int mi = 0; mi < 2; ++mi)
#pragma unroll
    for (int nt = 0; nt < 8; ++nt) acc[mi][nt] = (f32x4){0.f, 0.f, 0.f, 0.f};
  float m_ = -1e30f, l_ = 0.f;

  const u16* kp_base = Kb + kv * 512 + dbase;
  const u16* vt_base = Vt + (size_t)kv * (512 * 1024) + (size_t)dbase * 1024;
  int nst = (qbase + 31) / 64 + 1;

  for (int st = 0; st < nst; ++st) {
    int s0 = st * 64;
    f32x4 sa[2][4];
#pragma unroll
    for (int mi = 0; mi < 2; ++mi)
#pragma unroll
      for (int nt = 0; nt < 4; ++nt) sa[mi][nt] = (f32x4){0.f, 0.f, 0.f, 0.f};
#pragma unroll
    for (int ks = 0; ks < 4; ++ks) {
#pragma unroll
      for (int nt = 0; nt < 4; ++nt) {
        f16x8 kf = ld_h8(kp_base + (size_t)(s0 + nt * 16 + r15) * 2048 + ks * 32 + g * 8);
#pragma unroll
        for (int mi = 0; mi < 2; ++mi)
          sa[mi][nt] = MFMA16(qf[mi][ks], kf, sa[mi][nt]);
      }
    }
    {
      float* sw = Sred + w * 32 * 68;
#pragma unroll
      for (int mi = 0; mi < 2; ++mi)
#pragma unroll
        for (int nt = 0; nt < 4; ++nt)
#pragma unroll
          for (int r = 0; r < 4; ++r)
            sw[(mi * 16 + g * 4 + r) * 68 + nt * 16 + r15] = sa[mi][nt][r];
    }
    __syncthreads();

    {
      const float* sp = Sred + jrow * 68 + cl * 8;
      f32x4 a0 = *(const f32x4*)(sp);
      f32x4 a1 = *(const f32x4*)(sp + 4);
#pragma unroll
      for (int p = 1; p < 4; ++p) {
        a0 += *(const f32x4*)(sp + p * 32 * 68);
        a1 += *(const f32x4*)(sp + p * 32 * 68 + 4);
      }
      float sv[8];
      int sbase = s0 + cl * 8;
#pragma unroll
      for (int j = 0; j < 4; ++j) {
        sv[j]     = (sbase + j     <= qr_sm) ? a0[j] : -1e30f;
        sv[4 + j] = (sbase + 4 + j <= qr_sm) ? a1[j] : -1e30f;
      }
      float mm = sv[0];
#pragma unroll
      for (int j = 1; j < 8; ++j) mm = fmaxf(mm, sv[j]);
      mm = fmaxf(mm, __shfl_xor(mm, 1, 64));
      mm = fmaxf(mm, __shfl_xor(mm, 2, 64));
      mm = fmaxf(mm, __shfl_xor(mm, 4, 64));
      bool defer = (mm <= m_ + 8.f);
      float sc;
      if (defer) { sc = 1.f; }
      else { float mn = fmaxf(m_, mm); sc = __expf(m_ - mn); m_ = mn; }
      float pv8[8], rsum = 0.f;
#pragma unroll
      for (int j = 0; j < 8; ++j) { pv8[j] = __expf(sv[j] - m_); rsum += pv8[j]; }
      rsum += __shfl_xor(rsum, 1, 64);
      rsum += __shfl_xor(rsum, 2, 64);
      rsum += __shfl_xor(rsum, 4, 64);
      l_ = l_ * sc + rsum;
      u16x8 pw;
#pragma unroll
      for (int j = 0; j < 8; ++j) pw[j] = f2h_u(pv8[j]);
      *(u16x8*)(Plds + jrow * 64 + ((cl ^ (jrow & 7)) * 8)) = pw;
      if (cl == 0) scf[jrow] = sc;
      int need = __any((int)(!defer));
      if (lane == 0) nf[w] = need;
    }
    __syncthreads();

    if (nf[0] | nf[1] | nf[2] | nf[3]) {
#pragma unroll
      for (int mi = 0; mi < 2; ++mi)
#pragma unroll
        for (int r = 0; r < 4; ++r) {
          float s = scf[mi * 16 + g * 4 + r];
#pragma unroll
          for (int nt = 0; nt < 8; ++nt) acc[mi][nt][r] *= s;
        }
    }
    f16x8 pa[2][2];
#pragma unroll
    for (int mi = 0; mi < 2; ++mi)
#pragma unroll
      for (int ks = 0; ks < 2; ++ks) {
        int row = mi * 16 + r15;
        int c = ks * 4 + g;
        pa[mi][ks] = ld_h8(Plds + row * 64 + ((c ^ (row & 7)) * 8));
      }
#pragma unroll
    for (int ks = 0; ks < 2; ++ks)
#pragma unroll
      for (int nt = 0; nt < 8; ++nt) {
        f16x8 vf = ld_h8(vt_base + (size_t)(nt * 16 + r15) * 1024 + s0 + ks * 32 + g * 8);
#pragma unroll
        for (int mi = 0; mi < 2; ++mi)
          acc[mi][nt] = MFMA16(pa[mi][ks], vf, acc[mi][nt]);
      }
  }

  if (cl == 0) linv[jrow] = 1.0f / l_;
  __syncthreads();
#pragma unroll
  for (int mi = 0; mi < 2; ++mi)
#pragma unroll
    for (int r = 0; r < 4; ++r) {
      int row = mi * 16 + g * 4 + r;
      float li = linv[row];
      u16* yp = Y + (size_t)(qbase + row) * 16384 + h * 512 + dbase + r15;
#pragma unroll
      for (int nt = 0; nt < 8; ++nt)
        yp[nt * 16] = f2h_u(acc[mi][nt][r] * li);
    }
}

// ---------------------------------------------------------------------------
extern "C" void kernel_launch(void* const* d_in, const int* in_sizes, int n_in,
                              void* d_out, int out_size, void* d_ws, size_t ws_size,
                              hipStream_t stream)
{
  const float* x  = (const float*)d_in[0];
  const float* wq = (const float*)d_in[3];
  const float* wk = (const float*)d_in[4];
  const float* wo = (const float*)d_in[5];
  const float* qw = (const float*)d_in[6];
  const float* kw = (const float*)d_in[7];
  const float* fc = (const float*)d_in[10];
  const float* fs = (const float*)d_in[11];
  float* out = (float*)d_out;
  char* ws = (char*)d_ws;

  // ws layout (bytes):
  u16* Qbuf = (u16*)(ws + 0);            // [1024][16384] f16  32 MiB
  u16* Kbuf = (u16*)(ws + 33554432);     // [1024][2048]  f16   4 MiB
  u16* Vbuf = (u16*)(ws + 37748736);     // [1024][2048]  f16   4 MiB
  u16* Vt   = (u16*)(ws + 41943040);     // [4][512][1024] f16  4 MiB
  u16* Ybuf = (u16*)(ws + 46137344);     // [1024][16384] f16  32 MiB
  u16* xh   = (u16*)(ws + 79691776);     // [1024][5376]  f16  ~10.5 MiB
  // Split-K partials: wo uses Qbuf..Vt (44 MiB, dead after attention) as
  // 2x f32 slices; wk uses Ybuf (32 MiB, dead until attention) as 4x f32.
  float* Pb  = (float*)ws;               // 2 x [1024][5376] f32 = 44 MiB
  float* PbK = (float*)(ws + 46137344);  // 4 x [1024][2048] f32 = 32 MiB

  // 0) x -> f16
  convert_f32_f16<<<672, 256, 0, stream>>>(x, xh, (1024 * 5376) / 8);

  // 1) Q = x @ wq  (fused W-transpose GEMM, f16 out)
  gemm_ktn<false><<<dim3(128, 4, 1), 512, 0, stream>>>(
      xh, wq, (void*)Qbuf, 5376, 5376, 16384, 16384, 0L);

  // 2) Kraw = x @ wk : split-K x4 (f32 partials into PbK), reduce -> Kbuf f16
  gemm_ktn<true><<<dim3(16, 4, 4), 512, 0, stream>>>(
      xh, wk, (void*)PbK, 1344, 5376, 2048, 2048, 2097152L);
  reduce_add4_f16<<<2048, 256, 0, stream>>>(PbK, Kbuf, 524288, 2097152L);

  // 3) norms + rope
  norm_rope_q<<<dim3(1024, 32), 64, 0, stream>>>(Qbuf, qw, fc, fs);
  norm_kv<<<dim3(1024, 4), 64, 0, stream>>>(Kbuf, Vbuf, kw, fc, fs);
  // 4) Vt[kv][d][t] = V^T
  transpose_h16<<<dim3(8, 16, 4), 256, 0, stream>>>(
      Vbuf, Vt, 1024, 512, 2048, 1024, 512L, 524288L);
  // 5) attention -> Ybuf [t][h*512+d]
  attn2_kernel<<<dim3(32, 32), 256, 0, stream>>>(Qbuf, Kbuf, Vt, Ybuf);

  // 6) out = Y @ wo : split-K x2 (f32 partials into Pb), then reduce
  gemm_ktn<true><<<dim3(42, 4, 2), 512, 0, stream>>>(
      Ybuf, wo, (void*)Pb, 8192, 16384, 5376, 5376, 5505024L);
  reduce_add2_f32<<<2048, 256, 0, stream>>>(Pb, out, 1376256, 5505024L);
}

// Round 14
// 763.247 us; speedup vs baseline: 4.1281x; 4.1281x over previous
//
#include <hip/hip_runtime.h>
#include <stdint.h>

typedef unsigned short u16;
typedef _Float16 f16;
typedef f16 f16x8 __attribute__((ext_vector_type(8)));
typedef float f32x4 __attribute__((ext_vector_type(4)));
typedef unsigned short u16x4 __attribute__((ext_vector_type(4)));
typedef unsigned short u16x8 __attribute__((ext_vector_type(8)));

#define MFMA16(a, b, c) __builtin_amdgcn_mfma_f32_16x16x32_f16(a, b, c, 0, 0, 0)

__device__ __forceinline__ u16 f2h_u(float f) {
  union { f16 h; u16 u; } v; v.h = (f16)f; return v.u;
}
__device__ __forceinline__ float h2f(u16 u) {
  union { u16 u; f16 h; } v; v.u = u; return (float)v.h;
}
__device__ __forceinline__ f16x8 ld_h8(const u16* p) {
  return *(const f16x8*)p;
}
// async global->LDS, 16B per lane; LDS dest = wave-uniform base + lane*16
__device__ __forceinline__ void gl_lds16(const u16* g, u16* l) {
  __builtin_amdgcn_global_load_lds(
      (const __attribute__((address_space(1))) void*)g,
      (__attribute__((address_space(3))) void*)l, 16, 0, 0);
}

// ---------------------------------------------------------------------------
// f32 -> f16 elementwise convert (n8 = n/8 groups of 8)
// ---------------------------------------------------------------------------
__global__ __launch_bounds__(256) void convert_f32_f16(
    const float* __restrict__ in, u16* __restrict__ out, int n8)
{
  int i = blockIdx.x * 256 + threadIdx.x;
  int stride = gridDim.x * 256;
  for (; i < n8; i += stride) {
    f32x4 a = *(const f32x4*)(in + (size_t)i * 8);
    f32x4 b = *(const f32x4*)(in + (size_t)i * 8 + 4);
    u16x8 o;
#pragma unroll
    for (int j = 0; j < 4; ++j) { o[j] = f2h_u(a[j]); o[4 + j] = f2h_u(b[j]); }
    *(u16x8*)(out + (size_t)i * 8) = o;
  }
}

// ---------------------------------------------------------------------------
// f16-bits transpose (for V^T). Grid: (C/64, R/64, Z).
// ---------------------------------------------------------------------------
__global__ __launch_bounds__(256) void transpose_h16(
    const u16* __restrict__ in, u16* __restrict__ out,
    int R, int C, int ldi, int ldo, long zin, long zout)
{
  __shared__ u16 tile[64 * 66];
  const u16* ip = in + (size_t)blockIdx.z * zin;
  u16* op = out + (size_t)blockIdx.z * zout;
  int x0 = blockIdx.x * 64, y0 = blockIdx.y * 64;
  int t = threadIdx.x;
  int xr = (t & 15) * 4;
  int yr = t >> 4;
#pragma unroll
  for (int p = 0; p < 4; ++p) {
    int y = yr + p * 16;
    u16x4 v = *(const u16x4*)(ip + (size_t)(y0 + y) * ldi + x0 + xr);
    tile[y * 66 + xr + 0] = v.x;
    tile[y * 66 + xr + 1] = v.y;
    tile[y * 66 + xr + 2] = v.z;
    tile[y * 66 + xr + 3] = v.w;
  }
  __syncthreads();
#pragma unroll
  for (int p = 0; p < 4; ++p) {
    int x = (t >> 4) + p * 16;
    int yq = (t & 15) * 4;
    u16x4 v;
    v.x = tile[(yq + 0) * 66 + x];
    v.y = tile[(yq + 1) * 66 + x];
    v.z = tile[(yq + 2) * 66 + x];
    v.w = tile[(yq + 3) * 66 + x];
    *(u16x4*)(op + (size_t)(x0 + x) * ldo + y0 + yq) = v;
  }
}

// ---------------------------------------------------------------------------
// GEMM v6 (fused weight transpose): C[M][N] = A[M][K](f16) * W[K][N](f32).
// 256x128 tile, 8 waves, BK=32, 3 LDS buffers. A staged via gl_lds16
// (src-XOR-swizzled); B reg-staged: 8 coalesced f32 column loads -> f16x8 ->
// ds_write_b128 at chunk kc^((c>>1)&3) (matches frag-read swizzle).
// Single-barrier pipeline, counted vmcnt:
// queue at wait = [A(k+1) x2, B(k+1) x8, A(k+2) x2] -> vmcnt(2).
// Ktot clamps the K-range for non-uniform split-K: nk = min(Ksp, Ktot-kbeg)/32.
// Grid: (N/128, M/256, nz); split-K via blockIdx.z, partials at z*zstride.
// ---------------------------------------------------------------------------
template <bool F32OUT>
__global__ __launch_bounds__(512, 4) void gemm_ktn(
    const u16* __restrict__ A, const float* __restrict__ W, void* __restrict__ Cv,
    int Ksp, int Ktot, int lda, int ldw, int ldc, long zstride)
{
  __shared__ alignas(16) u16 As[3 * 256 * 32];   // 3 x 16 KB
  __shared__ alignas(16) u16 Bs[3 * 128 * 32];   // 3 x  8 KB
  int tid = threadIdx.x;
  int lane = tid & 63;
  int wave = tid >> 6;
  int wm = wave >> 2, wn = wave & 3;
  int r15 = lane & 15, g = lane >> 4;

  // XCD-bijective swizzle + column-major (M fastest) decomposition
  int gx = gridDim.x, gy = gridDim.y;
  int nwg = gx * gy;
  int flat = blockIdx.y * gx + blockIdx.x;
  int q = nwg >> 3, rr = nwg & 7, xcd = flat & 7, lo = flat >> 3;
  int s = ((xcd < rr) ? xcd * (q + 1) : rr * (q + 1) + (xcd - rr) * q) + lo;
  int by = s % gy;
  int bx = s / gy;
  int row0 = by * 256, col0 = bx * 128;
  int kbeg = blockIdx.z * Ksp;
  int krem = Ktot - kbeg;
  int klen = (krem < Ksp) ? krem : Ksp;

  // A staging: lane covers LDS row tid>>2, 16B chunk tid&3, src XOR-swizzled
  int rA = tid >> 2;
  int pc = tid & 3;
  int cs = pc ^ ((rA >> 1) & 3);
  const u16* Ag0 = A + (size_t)(row0 + rA) * lda + kbeg + cs * 8;  // rows 0..127
  const u16* Ag1 = Ag0 + (size_t)128 * lda;                        // rows 128..255

  // B staging: col cB (coalesced across lanes), k-chunk kc (8 k each)
  int cB = tid & 127;
  int kc = tid >> 7;
  const float* Wg = W + (size_t)(kbeg + kc * 8) * ldw + col0 + cB;
  int bwoff = cB * 32 + ((kc ^ ((cB >> 1) & 3)) * 8);  // u16 units

  f32x4 acc[8][2];
#pragma unroll
  for (int i = 0; i < 8; ++i)
#pragma unroll
    for (int j = 0; j < 2; ++j) acc[i][j] = (f32x4){0.f, 0.f, 0.f, 0.f};

  int nk = klen >> 5;
  float bw[8];

  auto BLOAD = [&](int kk) {          // tile kk's 8 column f32 loads
#pragma unroll
    for (int j = 0; j < 8; ++j)
      bw[j] = Wg[(size_t)(kk * 32 + j) * ldw];
  };
  auto BWRITE = [&](int b) {          // convert + swizzled ds_write_b128
    u16x8 o;
#pragma unroll
    for (int j = 0; j < 8; ++j) o[j] = f2h_u(bw[j]);
    *(u16x8*)(Bs + b * 4096 + bwoff) = o;
  };
  auto STAGE_A = [&](int kk, int b) {
    u16* la = As + b * 8192 + wave * 512;
    gl_lds16(Ag0 + (size_t)kk * 32, la);
    gl_lds16(Ag1 + (size_t)kk * 32, la + 4096);
  };

  // prologue: B0 + A0 + A1 issued; confirm B0+A0 (A1 stays in flight)
  BLOAD(0);
  STAGE_A(0, 0);
  if (nk > 1) STAGE_A(1, 1);
  asm volatile("s_waitcnt vmcnt(2)" ::: "memory");
  BWRITE(0);
  asm volatile("s_waitcnt lgkmcnt(0)" ::: "memory");
  __builtin_amdgcn_s_barrier();

  int swz = (g ^ ((r15 >> 1) & 3)) * 8;
  int b0 = 0;
  for (int k = 0; k < nk; ++k) {
    const u16* Ab = As + b0 * 8192;
    const u16* Bb = Bs + b0 * 4096;
    // issue long-latency loads first
    if (k + 1 < nk) BLOAD(k + 1);
    if (k + 2 < nk) {
      int b2 = b0 + 2; if (b2 >= 3) b2 -= 3;
      STAGE_A(k + 2, b2);
    }
    // frag reads for tile k (published by previous barrier)
    f16x8 bfr[2], af[4];
#pragma unroll
    for (int ni = 0; ni < 2; ++ni)
      bfr[ni] = ld_h8(Bb + (wn * 32 + ni * 16 + r15) * 32 + swz);
#pragma unroll
    for (int m2 = 0; m2 < 4; ++m2)
      af[m2] = ld_h8(Ab + (wm * 128 + m2 * 16 + r15) * 32 + swz);
    __builtin_amdgcn_s_setprio(1);
#pragma unroll
    for (int m2 = 0; m2 < 4; ++m2)
#pragma unroll
      for (int ni = 0; ni < 2; ++ni)
        acc[m2][ni] = MFMA16(af[m2], bfr[ni], acc[m2][ni]);
    f16x8 ag[4];
#pragma unroll
    for (int m2 = 0; m2 < 4; ++m2)
      ag[m2] = ld_h8(Ab + (wm * 128 + (4 + m2) * 16 + r15) * 32 + swz);
#pragma unroll
    for (int m2 = 0; m2 < 4; ++m2)
#pragma unroll
      for (int ni = 0; ni < 2; ++ni)
        acc[4 + m2][ni] = MFMA16(ag[m2], bfr[ni], acc[4 + m2][ni]);
    __builtin_amdgcn_s_setprio(0);
    // confirm A(k+1)+B(k+1); leave A(k+2) in flight; write B(k+1) to its buf
    if (k + 1 < nk) {
      if (k + 2 < nk) {
        asm volatile("s_waitcnt vmcnt(2)" ::: "memory");
      } else {
        asm volatile("s_waitcnt vmcnt(0)" ::: "memory");
      }
      int b1 = b0 + 1; if (b1 >= 3) b1 -= 3;
      BWRITE(b1);
    }
    asm volatile("s_waitcnt lgkmcnt(0)" ::: "memory");
    __builtin_amdgcn_s_barrier();   // publishes tile k+1 (A DMA + B ds_write)
    b0 = (b0 == 2) ? 0 : b0 + 1;
  }

  // C/D layout: col = lane&15, row = (lane>>4)*4 + reg
#pragma unroll
  for (int mi = 0; mi < 8; ++mi)
#pragma unroll
    for (int ni = 0; ni < 2; ++ni) {
      int row = row0 + wm * 128 + mi * 16 + g * 4;
      int col = col0 + wn * 32 + ni * 16 + r15;
#pragma unroll
      for (int r = 0; r < 4; ++r) {
        if constexpr (F32OUT)
          ((float*)Cv)[(size_t)blockIdx.z * zstride + (size_t)(row + r) * ldc + col] = acc[mi][ni][r];
        else
          ((u16*)Cv)[(size_t)blockIdx.z * zstride + (size_t)(row + r) * ldc + col] = f2h_u(acc[mi][ni][r]);
      }
    }
}

// ---------------------------------------------------------------------------
// out_f16[i] = sum of 4 f32 partial slices (n4 = n/4 groups of 4)
// ---------------------------------------------------------------------------
__global__ __launch_bounds__(256) void reduce_add4_f16(
    const float* __restrict__ p, u16* __restrict__ out, int n4, long zs)
{
  int i = blockIdx.x * 256 + threadIdx.x;
  int stride = gridDim.x * 256;
  for (; i < n4; i += stride) {
    f32x4 a = *(const f32x4*)(p + (size_t)i * 4);
    a += *(const f32x4*)(p + zs + (size_t)i * 4);
    a += *(const f32x4*)(p + 2 * zs + (size_t)i * 4);
    a += *(const f32x4*)(p + 3 * zs + (size_t)i * 4);
    u16x4 o;
#pragma unroll
    for (int j = 0; j < 4; ++j) o[j] = f2h_u(a[j]);
    *(u16x4*)(out + (size_t)i * 4) = o;
  }
}

// ---------------------------------------------------------------------------
// out_f32[i] = sum of 3 f16 partial slices (n8 = n/8 groups of 8)
// ---------------------------------------------------------------------------
__global__ __launch_bounds__(256) void reduce_add3_h_f32(
    const u16* __restrict__ p, float* __restrict__ out, int n8, long zs)
{
  int i = blockIdx.x * 256 + threadIdx.x;
  int stride = gridDim.x * 256;
  for (; i < n8; i += stride) {
    u16x8 a0 = *(const u16x8*)(p + (size_t)i * 8);
    u16x8 a1 = *(const u16x8*)(p + zs + (size_t)i * 8);
    u16x8 a2 = *(const u16x8*)(p + 2 * zs + (size_t)i * 8);
    f32x4 o0, o1;
#pragma unroll
    for (int j = 0; j < 4; ++j) {
      o0[j] = h2f(a0[j]) + h2f(a1[j]) + h2f(a2[j]);
      o1[j] = h2f(a0[4 + j]) + h2f(a1[4 + j]) + h2f(a2[4 + j]);
    }
    *(f32x4*)(out + (size_t)i * 8) = o0;
    *(f32x4*)(out + (size_t)i * 8 + 4) = o1;
  }
}

// ---------------------------------------------------------------------------
// Per-(t, head) RMSNorm(*w) + RoPE for Q (f16 in place; w, freqs f32).
// ---------------------------------------------------------------------------
__global__ __launch_bounds__(64) void norm_rope_q(
    u16* __restrict__ q, const float* __restrict__ w,
    const float* __restrict__ fc, const float* __restrict__ fs)
{
  int t = blockIdx.x, h = blockIdx.y, lane = threadIdx.x;
  u16* row = q + (size_t)t * 16384 + h * 512;
  u16x8 v = *(const u16x8*)(row + lane * 8);
  float x[8];
  float ss = 0.f;
#pragma unroll
  for (int j = 0; j < 8; ++j) { x[j] = h2f(v[j]); ss += x[j] * x[j]; }
#pragma unroll
  for (int m = 1; m < 64; m <<= 1) ss += __shfl_xor(ss, m, 64);
  float rms = rsqrtf(ss * (1.f / 512.f) + 1e-6f);
  f32x4 w0 = *(const f32x4*)(w + lane * 8);
  f32x4 w1 = *(const f32x4*)(w + lane * 8 + 4);
  float y[8];
#pragma unroll
  for (int j = 0; j < 4; ++j) {
    y[j] = x[j] * rms * w0[j];
    y[4 + j] = x[4 + j] * rms * w1[j];
  }
  if (lane < 16) {
    f32x4 cv = *(const f32x4*)(fc + t * 64 + lane * 4);
    f32x4 sv = *(const f32x4*)(fs + t * 64 + lane * 4);
#pragma unroll
    for (int j = 0; j < 4; ++j) {
      float c = cv[j], s = sv[j];
      float a = y[2 * j], b = y[2 * j + 1];
      y[2 * j] = a * c - b * s;
      y[2 * j + 1] = a * s + b * c;
    }
  }
  u16x8 o;
#pragma unroll
  for (int j = 0; j < 8; ++j) o[j] = f2h_u(y[j]);
  *(u16x8*)(row + lane * 8) = o;
}

// ---------------------------------------------------------------------------
// Per-(t, kv): shared sumsq; k = rms*k_w + RoPE (in place), v = rms (-> vout).
// ---------------------------------------------------------------------------
__global__ __launch_bounds__(64) void norm_kv(
    u16* __restrict__ kraw, u16* __restrict__ vout, const float* __restrict__ kw,
    const float* __restrict__ fc, const float* __restrict__ fs)
{
  int t = blockIdx.x, kv = blockIdx.y, lane = threadIdx.x;
  u16* row  = kraw + (size_t)t * 2048 + kv * 512;
  u16* vrow = vout + (size_t)t * 2048 + kv * 512;
  u16x8 v = *(const u16x8*)(row + lane * 8);
  float x[8];
  float ss = 0.f;
#pragma unroll
  for (int j = 0; j < 8; ++j) { x[j] = h2f(v[j]); ss += x[j] * x[j]; }
#pragma unroll
  for (int m = 1; m < 64; m <<= 1) ss += __shfl_xor(ss, m, 64);
  float rms = rsqrtf(ss * (1.f / 512.f) + 1e-6f);
  f32x4 w0 = *(const f32x4*)(kw + lane * 8);
  f32x4 w1 = *(const f32x4*)(kw + lane * 8 + 4);
  float yk[8], yv[8];
#pragma unroll
  for (int j = 0; j < 4; ++j) {
    yv[j] = x[j] * rms;           yv[4 + j] = x[4 + j] * rms;
    yk[j] = yv[j] * w0[j];        yk[4 + j] = yv[4 + j] * w1[j];
  }
  if (lane < 16) {
    f32x4 cv = *(const f32x4*)(fc + t * 64 + lane * 4);
    f32x4 sv = *(const f32x4*)(fs + t * 64 + lane * 4);
#pragma unroll
    for (int j = 0; j < 4; ++j) {
      float c = cv[j], s = sv[j];
      float a = yk[2 * j], b = yk[2 * j + 1];
      yk[2 * j] = a * c - b * s;
      yk[2 * j + 1] = a * s + b * c;
    }
  }
  u16x8 ok, ov;
#pragma unroll
  for (int j = 0; j < 8; ++j) { ok[j] = f2h_u(yk[j]); ov[j] = f2h_u(yv[j]); }
  *(u16x8*)(row + lane * 8) = ok;
  *(u16x8*)(vrow + lane * 8) = ov;
}

// ---------------------------------------------------------------------------
// Flash attention v2: 4-wave block, 32 q-rows, D=512 split 4x128 across waves.
// ---------------------------------------------------------------------------
__global__ __launch_bounds__(256) void attn2_kernel(
    const u16* __restrict__ Q, const u16* __restrict__ Kb,
    const u16* __restrict__ Vt, u16* __restrict__ Y)
{
  __shared__ float Sred[4 * 32 * 68];
  __shared__ u16 Plds[32 * 64];
  __shared__ float scf[32];
  __shared__ float linv[32];
  __shared__ int nf[4];

  int h = blockIdx.x;
  int qtb = 31 - blockIdx.y;
  int kv = h >> 3;
  int tid = threadIdx.x;
  int lane = tid & 63;
  int w = tid >> 6;
  int r15 = lane & 15, g = lane >> 4;
  int qbase = qtb * 32;
  int dbase = w * 128;

  int jloc = lane >> 3, cl = lane & 7;
  int jrow = w * 8 + jloc;
  int qr_sm = qbase + jrow;

  f16x8 qf[2][4];
  {
    const u16* qp = Q + (size_t)(qbase + r15) * 16384 + h * 512 + dbase + g * 8;
#pragma unroll
    for (int mi = 0; mi < 2; ++mi)
#pragma unroll
      for (int ks = 0; ks < 4; ++ks)
        qf[mi][ks] = ld_h8(qp + (size_t)mi * 16 * 16384 + ks * 32);
  }

  f32x4 acc[2][8];
#pragma unroll
  for (int mi = 0; mi < 2; ++mi)
#pragma unroll
    for (int nt = 0; nt < 8; ++nt) acc[mi][nt] = (f32x4){0.f, 0.f, 0.f, 0.f};
  float m_ = -1e30f, l_ = 0.f;

  const u16* kp_base = Kb + kv * 512 + dbase;
  const u16* vt_base = Vt + (size_t)kv * (512 * 1024) + (size_t)dbase * 1024;
  int nst = (qbase + 31) / 64 + 1;

  for (int st = 0; st < nst; ++st) {
    int s0 = st * 64;
    f32x4 sa[2][4];
#pragma unroll
    for (int mi = 0; mi < 2; ++mi)
#pragma unroll
      for (int nt = 0; nt < 4; ++nt) sa[mi][nt] = (f32x4){0.f, 0.f, 0.f, 0.f};
#pragma unroll
    for (int ks = 0; ks < 4; ++ks) {
#pragma unroll
      for (int nt = 0; nt < 4; ++nt) {
        f16x8 kf = ld_h8(kp_base + (size_t)(s0 + nt * 16 + r15) * 2048 + ks * 32 + g * 8);
#pragma unroll
        for (int mi = 0; mi < 2; ++mi)
          sa[mi][nt] = MFMA16(qf[mi][ks], kf, sa[mi][nt]);
      }
    }
    {
      float* sw = Sred + w * 32 * 68;
#pragma unroll
      for (int mi = 0; mi < 2; ++mi)
#pragma unroll
        for (int nt = 0; nt < 4; ++nt)
#pragma unroll
          for (int r = 0; r < 4; ++r)
            sw[(mi * 16 + g * 4 + r) * 68 + nt * 16 + r15] = sa[mi][nt][r];
    }
    __syncthreads();

    {
      const float* sp = Sred + jrow * 68 + cl * 8;
      f32x4 a0 = *(const f32x4*)(sp);
      f32x4 a1 = *(const f32x4*)(sp + 4);
#pragma unroll
      for (int p = 1; p < 4; ++p) {
        a0 += *(const f32x4*)(sp + p * 32 * 68);
        a1 += *(const f32x4*)(sp + p * 32 * 68 + 4);
      }
      float sv[8];
      int sbase = s0 + cl * 8;
#pragma unroll
      for (int j = 0; j < 4; ++j) {
        sv[j]     = (sbase + j     <= qr_sm) ? a0[j] : -1e30f;
        sv[4 + j] = (sbase + 4 + j <= qr_sm) ? a1[j] : -1e30f;
      }
      float mm = sv[0];
#pragma unroll
      for (int j = 1; j < 8; ++j) mm = fmaxf(mm, sv[j]);
      mm = fmaxf(mm, __shfl_xor(mm, 1, 64));
      mm = fmaxf(mm, __shfl_xor(mm, 2, 64));
      mm = fmaxf(mm, __shfl_xor(mm, 4, 64));
      bool defer = (mm <= m_ + 8.f);
      float sc;
      if (defer) { sc = 1.f; }
      else { float mn = fmaxf(m_, mm); sc = __expf(m_ - mn); m_ = mn; }
      float pv8[8], rsum = 0.f;
#pragma unroll
      for (int j = 0; j < 8; ++j) { pv8[j] = __expf(sv[j] - m_); rsum += pv8[j]; }
      rsum += __shfl_xor(rsum, 1, 64);
      rsum += __shfl_xor(rsum, 2, 64);
      rsum += __shfl_xor(rsum, 4, 64);
      l_ = l_ * sc + rsum;
      u16x8 pw;
#pragma unroll
      for (int j = 0; j < 8; ++j) pw[j] = f2h_u(pv8[j]);
      *(u16x8*)(Plds + jrow * 64 + ((cl ^ (jrow & 7)) * 8)) = pw;
      if (cl == 0) scf[jrow] = sc;
      int need = __any((int)(!defer));
      if (lane == 0) nf[w] = need;
    }
    __syncthreads();

    if (nf[0] | nf[1] | nf[2] | nf[3]) {
#pragma unroll
      for (int mi = 0; mi < 2; ++mi)
#pragma unroll
        for (int r = 0; r < 4; ++r) {
          float s = scf[mi * 16 + g * 4 + r];
#pragma unroll
          for (int nt = 0; nt < 8; ++nt) acc[mi][nt][r] *= s;
        }
    }
    f16x8 pa[2][2];
#pragma unroll
    for (int mi = 0; mi < 2; ++mi)
#pragma unroll
      for (int ks = 0; ks < 2; ++ks) {
        int row = mi * 16 + r15;
        int c = ks * 4 + g;
        pa[mi][ks] = ld_h8(Plds + row * 64 + ((c ^ (row & 7)) * 8));
      }
#pragma unroll
    for (int ks = 0; ks < 2; ++ks)
#pragma unroll
      for (int nt = 0; nt < 8; ++nt) {
        f16x8 vf = ld_h8(vt_base + (size_t)(nt * 16 + r15) * 1024 + s0 + ks * 32 + g * 8);
#pragma unroll
        for (int mi = 0; mi < 2; ++mi)
          acc[mi][nt] = MFMA16(pa[mi][ks], vf, acc[mi][nt]);
      }
  }

  if (cl == 0) linv[jrow] = 1.0f / l_;
  __syncthreads();
#pragma unroll
  for (int mi = 0; mi < 2; ++mi)
#pragma unroll
    for (int r = 0; r < 4; ++r) {
      int row = mi * 16 + g * 4 + r;
      float li = linv[row];
      u16* yp = Y + (size_t)(qbase + row) * 16384 + h * 512 + dbase + r15;
#pragma unroll
      for (int nt = 0; nt < 8; ++nt)
        yp[nt * 16] = f2h_u(acc[mi][nt][r] * li);
    }
}

// ---------------------------------------------------------------------------
extern "C" void kernel_launch(void* const* d_in, const int* in_sizes, int n_in,
                              void* d_out, int out_size, void* d_ws, size_t ws_size,
                              hipStream_t stream)
{
  const float* x  = (const float*)d_in[0];
  const float* wq = (const float*)d_in[3];
  const float* wk = (const float*)d_in[4];
  const float* wo = (const float*)d_in[5];
  const float* qw = (const float*)d_in[6];
  const float* kw = (const float*)d_in[7];
  const float* fc = (const float*)d_in[10];
  const float* fs = (const float*)d_in[11];
  float* out = (float*)d_out;
  char* ws = (char*)d_ws;

  // ws layout (bytes):
  u16* Qbuf = (u16*)(ws + 0);            // [1024][16384] f16  32 MiB
  u16* Kbuf = (u16*)(ws + 33554432);     // [1024][2048]  f16   4 MiB
  u16* Vbuf = (u16*)(ws + 37748736);     // [1024][2048]  f16   4 MiB
  u16* Vt   = (u16*)(ws + 41943040);     // [4][512][1024] f16  4 MiB
  u16* Ybuf = (u16*)(ws + 46137344);     // [1024][16384] f16  32 MiB
  u16* xh   = (u16*)(ws + 79691776);     // [1024][5376]  f16  ~10.5 MiB
  // Split-K partials: wo uses Qbuf region (dead after attention) as 3x f16
  // slices (31.5 MiB < 32 MiB); wk uses Ybuf (dead until attention) as 4x f32.
  u16* PbH   = (u16*)ws;                 // 3 x [1024][5376] f16
  float* PbK = (float*)(ws + 46137344);  // 4 x [1024][2048] f32 = 32 MiB

  // 0) x -> f16
  convert_f32_f16<<<672, 256, 0, stream>>>(x, xh, (1024 * 5376) / 8);

  // 1) Q = x @ wq  (fused W-transpose GEMM, f16 out)
  gemm_ktn<false><<<dim3(128, 4, 1), 512, 0, stream>>>(
      xh, wq, (void*)Qbuf, 5376, 5376, 5376, 16384, 16384, 0L);

  // 2) Kraw = x @ wk : split-K x4 (f32 partials into PbK), reduce -> Kbuf f16
  gemm_ktn<true><<<dim3(16, 4, 4), 512, 0, stream>>>(
      xh, wk, (void*)PbK, 1344, 5376, 5376, 2048, 2048, 2097152L);
  reduce_add4_f16<<<2048, 256, 0, stream>>>(PbK, Kbuf, 524288, 2097152L);

  // 3) norms + rope
  norm_rope_q<<<dim3(1024, 32), 64, 0, stream>>>(Qbuf, qw, fc, fs);
  norm_kv<<<dim3(1024, 4), 64, 0, stream>>>(Kbuf, Vbuf, kw, fc, fs);
  // 4) Vt[kv][d][t] = V^T
  transpose_h16<<<dim3(8, 16, 4), 256, 0, stream>>>(
      Vbuf, Vt, 1024, 512, 2048, 1024, 512L, 524288L);
  // 5) attention -> Ybuf [t][h*512+d]
  attn2_kernel<<<dim3(32, 32), 256, 0, stream>>>(Qbuf, Kbuf, Vt, Ybuf);

  // 6) out = Y @ wo : split-K x3 (f16 partials into PbH, non-uniform
  //    171/171/170 K-steps via Ktot clamp), reduce -> out f32
  gemm_ktn<false><<<dim3(42, 4, 3), 512, 0, stream>>>(
      Ybuf, wo, (void*)PbH, 5472, 16384, 16384, 5376, 5376, 5505024L);
  reduce_add3_h_f32<<<2048, 256, 0, stream>>>(PbH, out, 688128, 5505024L);
}

// Round 15
// 754.405 us; speedup vs baseline: 4.1765x; 1.0117x over previous
//
#include <hip/hip_runtime.h>
#include <stdint.h>

typedef unsigned short u16;
typedef _Float16 f16;
typedef f16 f16x8 __attribute__((ext_vector_type(8)));
typedef float f32x4 __attribute__((ext_vector_type(4)));
typedef unsigned short u16x4 __attribute__((ext_vector_type(4)));
typedef unsigned short u16x8 __attribute__((ext_vector_type(8)));

#define MFMA16(a, b, c) __builtin_amdgcn_mfma_f32_16x16x32_f16(a, b, c, 0, 0, 0)

__device__ __forceinline__ u16 f2h_u(float f) {
  union { f16 h; u16 u; } v; v.h = (f16)f; return v.u;
}
__device__ __forceinline__ float h2f(u16 u) {
  union { u16 u; f16 h; } v; v.u = u; return (float)v.h;
}
__device__ __forceinline__ f16x8 ld_h8(const u16* p) {
  return *(const f16x8*)p;
}
// async global->LDS, 16B per lane; LDS dest = wave-uniform base + lane*16
__device__ __forceinline__ void gl_lds16(const u16* g, u16* l) {
  __builtin_amdgcn_global_load_lds(
      (const __attribute__((address_space(1))) void*)g,
      (__attribute__((address_space(3))) void*)l, 16, 0, 0);
}

// ---------------------------------------------------------------------------
// f32 -> f16 elementwise convert (n8 = n/8 groups of 8)
// ---------------------------------------------------------------------------
__global__ __launch_bounds__(256) void convert_f32_f16(
    const float* __restrict__ in, u16* __restrict__ out, int n8)
{
  int i = blockIdx.x * 256 + threadIdx.x;
  int stride = gridDim.x * 256;
  for (; i < n8; i += stride) {
    f32x4 a = *(const f32x4*)(in + (size_t)i * 8);
    f32x4 b = *(const f32x4*)(in + (size_t)i * 8 + 4);
    u16x8 o;
#pragma unroll
    for (int j = 0; j < 4; ++j) { o[j] = f2h_u(a[j]); o[4 + j] = f2h_u(b[j]); }
    *(u16x8*)(out + (size_t)i * 8) = o;
  }
}

// ---------------------------------------------------------------------------
// f16-bits transpose (for V^T). Grid: (C/64, R/64, Z).
// ---------------------------------------------------------------------------
__global__ __launch_bounds__(256) void transpose_h16(
    const u16* __restrict__ in, u16* __restrict__ out,
    int R, int C, int ldi, int ldo, long zin, long zout)
{
  __shared__ u16 tile[64 * 66];
  const u16* ip = in + (size_t)blockIdx.z * zin;
  u16* op = out + (size_t)blockIdx.z * zout;
  int x0 = blockIdx.x * 64, y0 = blockIdx.y * 64;
  int t = threadIdx.x;
  int xr = (t & 15) * 4;
  int yr = t >> 4;
#pragma unroll
  for (int p = 0; p < 4; ++p) {
    int y = yr + p * 16;
    u16x4 v = *(const u16x4*)(ip + (size_t)(y0 + y) * ldi + x0 + xr);
    tile[y * 66 + xr + 0] = v.x;
    tile[y * 66 + xr + 1] = v.y;
    tile[y * 66 + xr + 2] = v.z;
    tile[y * 66 + xr + 3] = v.w;
  }
  __syncthreads();
#pragma unroll
  for (int p = 0; p < 4; ++p) {
    int x = (t >> 4) + p * 16;
    int yq = (t & 15) * 4;
    u16x4 v;
    v.x = tile[(yq + 0) * 66 + x];
    v.y = tile[(yq + 1) * 66 + x];
    v.z = tile[(yq + 2) * 66 + x];
    v.w = tile[(yq + 3) * 66 + x];
    *(u16x4*)(op + (size_t)(x0 + x) * ldo + y0 + yq) = v;
  }
}

// ---------------------------------------------------------------------------
// GEMM v6b (fused weight transpose): C[M][N] = A[M][K](f16) * W[K][N](f32).
// 256x128 tile, 8 waves, BK=32, 3 LDS buffers. A staged via gl_lds16
// (src-XOR-swizzled); B reg-staged: 8 coalesced f32 column loads -> f16x8 ->
// ds_write_b128 at chunk kc^((c>>1)&3). Single-barrier pipeline, counted
// vmcnt: queue at wait = [A(k+1) x2, B(k+1) x8, A(k+2) x2] -> vmcnt(2).
// Ktot clamps K for non-uniform split-K. bxfast selects supertile order:
// 1 = col-fastest (co-XCD blocks share ONE A M-panel -> A L2-resident; use
// when A-panel = 256*K*2B fits 4MB L2), 0 = row-fastest (W-panel reuse).
// Grid: (N/128, M/256, nz); split-K via blockIdx.z, partials at z*zstride.
// ---------------------------------------------------------------------------
template <bool F32OUT>
__global__ __launch_bounds__(512, 4) void gemm_ktn(
    const u16* __restrict__ A, const float* __restrict__ W, void* __restrict__ Cv,
    int Ksp, int Ktot, int bxfast, int lda, int ldw, int ldc, long zstride)
{
  __shared__ alignas(16) u16 As[3 * 256 * 32];   // 3 x 16 KB
  __shared__ alignas(16) u16 Bs[3 * 128 * 32];   // 3 x  8 KB
  int tid = threadIdx.x;
  int lane = tid & 63;
  int wave = tid >> 6;
  int wm = wave >> 2, wn = wave & 3;
  int r15 = lane & 15, g = lane >> 4;

  // XCD-bijective swizzle + supertile decomposition (bxfast selects order)
  int gx = gridDim.x, gy = gridDim.y;
  int nwg = gx * gy;
  int flat = blockIdx.y * gx + blockIdx.x;
  int q = nwg >> 3, rr = nwg & 7, xcd = flat & 7, lo = flat >> 3;
  int s = ((xcd < rr) ? xcd * (q + 1) : rr * (q + 1) + (xcd - rr) * q) + lo;
  int by, bx;
  if (bxfast) { bx = s % gx; by = s / gx; }
  else        { by = s % gy; bx = s / gy; }
  int row0 = by * 256, col0 = bx * 128;
  int kbeg = blockIdx.z * Ksp;
  int krem = Ktot - kbeg;
  int klen = (krem < Ksp) ? krem : Ksp;

  // A staging: lane covers LDS row tid>>2, 16B chunk tid&3, src XOR-swizzled
  int rA = tid >> 2;
  int pc = tid & 3;
  int cs = pc ^ ((rA >> 1) & 3);
  const u16* Ag0 = A + (size_t)(row0 + rA) * lda + kbeg + cs * 8;  // rows 0..127
  const u16* Ag1 = Ag0 + (size_t)128 * lda;                        // rows 128..255

  // B staging: col cB (coalesced across lanes), k-chunk kc (8 k each)
  int cB = tid & 127;
  int kc = tid >> 7;
  const float* Wg = W + (size_t)(kbeg + kc * 8) * ldw + col0 + cB;
  int bwoff = cB * 32 + ((kc ^ ((cB >> 1) & 3)) * 8);  // u16 units

  f32x4 acc[8][2];
#pragma unroll
  for (int i = 0; i < 8; ++i)
#pragma unroll
    for (int j = 0; j < 2; ++j) acc[i][j] = (f32x4){0.f, 0.f, 0.f, 0.f};

  int nk = klen >> 5;
  float bw[8];

  auto BLOAD = [&](int kk) {          // tile kk's 8 column f32 loads
#pragma unroll
    for (int j = 0; j < 8; ++j)
      bw[j] = Wg[(size_t)(kk * 32 + j) * ldw];
  };
  auto BWRITE = [&](int b) {          // convert + swizzled ds_write_b128
    u16x8 o;
#pragma unroll
    for (int j = 0; j < 8; ++j) o[j] = f2h_u(bw[j]);
    *(u16x8*)(Bs + b * 4096 + bwoff) = o;
  };
  auto STAGE_A = [&](int kk, int b) {
    u16* la = As + b * 8192 + wave * 512;
    gl_lds16(Ag0 + (size_t)kk * 32, la);
    gl_lds16(Ag1 + (size_t)kk * 32, la + 4096);
  };

  // prologue: B0 + A0 + A1 issued; confirm B0+A0 (A1 stays in flight)
  BLOAD(0);
  STAGE_A(0, 0);
  if (nk > 1) STAGE_A(1, 1);
  asm volatile("s_waitcnt vmcnt(2)" ::: "memory");
  BWRITE(0);
  asm volatile("s_waitcnt lgkmcnt(0)" ::: "memory");
  __builtin_amdgcn_s_barrier();

  int swz = (g ^ ((r15 >> 1) & 3)) * 8;
  int b0 = 0;
  for (int k = 0; k < nk; ++k) {
    const u16* Ab = As + b0 * 8192;
    const u16* Bb = Bs + b0 * 4096;
    // issue long-latency loads first
    if (k + 1 < nk) BLOAD(k + 1);
    if (k + 2 < nk) {
      int b2 = b0 + 2; if (b2 >= 3) b2 -= 3;
      STAGE_A(k + 2, b2);
    }
    // frag reads for tile k (published by previous barrier)
    f16x8 bfr[2], af[4];
#pragma unroll
    for (int ni = 0; ni < 2; ++ni)
      bfr[ni] = ld_h8(Bb + (wn * 32 + ni * 16 + r15) * 32 + swz);
#pragma unroll
    for (int m2 = 0; m2 < 4; ++m2)
      af[m2] = ld_h8(Ab + (wm * 128 + m2 * 16 + r15) * 32 + swz);
    __builtin_amdgcn_s_setprio(1);
#pragma unroll
    for (int m2 = 0; m2 < 4; ++m2)
#pragma unroll
      for (int ni = 0; ni < 2; ++ni)
        acc[m2][ni] = MFMA16(af[m2], bfr[ni], acc[m2][ni]);
    f16x8 ag[4];
#pragma unroll
    for (int m2 = 0; m2 < 4; ++m2)
      ag[m2] = ld_h8(Ab + (wm * 128 + (4 + m2) * 16 + r15) * 32 + swz);
#pragma unroll
    for (int m2 = 0; m2 < 4; ++m2)
#pragma unroll
      for (int ni = 0; ni < 2; ++ni)
        acc[4 + m2][ni] = MFMA16(ag[m2], bfr[ni], acc[4 + m2][ni]);
    __builtin_amdgcn_s_setprio(0);
    // confirm A(k+1)+B(k+1); leave A(k+2) in flight; write B(k+1) to its buf
    if (k + 1 < nk) {
      if (k + 2 < nk) {
        asm volatile("s_waitcnt vmcnt(2)" ::: "memory");
      } else {
        asm volatile("s_waitcnt vmcnt(0)" ::: "memory");
      }
      int b1 = b0 + 1; if (b1 >= 3) b1 -= 3;
      BWRITE(b1);
    }
    asm volatile("s_waitcnt lgkmcnt(0)" ::: "memory");
    __builtin_amdgcn_s_barrier();   // publishes tile k+1 (A DMA + B ds_write)
    b0 = (b0 == 2) ? 0 : b0 + 1;
  }

  // C/D layout: col = lane&15, row = (lane>>4)*4 + reg
#pragma unroll
  for (int mi = 0; mi < 8; ++mi)
#pragma unroll
    for (int ni = 0; ni < 2; ++ni) {
      int row = row0 + wm * 128 + mi * 16 + g * 4;
      int col = col0 + wn * 32 + ni * 16 + r15;
#pragma unroll
      for (int r = 0; r < 4; ++r) {
        if constexpr (F32OUT)
          ((float*)Cv)[(size_t)blockIdx.z * zstride + (size_t)(row + r) * ldc + col] = acc[mi][ni][r];
        else
          ((u16*)Cv)[(size_t)blockIdx.z * zstride + (size_t)(row + r) * ldc + col] = f2h_u(acc[mi][ni][r]);
      }
    }
}

// ---------------------------------------------------------------------------
// out_f16[i] = sum of 8 f16 partial slices (n8 = n/8 groups of 8)
// ---------------------------------------------------------------------------
__global__ __launch_bounds__(256) void reduce_add8_h_f16(
    const u16* __restrict__ p, u16* __restrict__ out, int n8, long zs)
{
  int i = blockIdx.x * 256 + threadIdx.x;
  int stride = gridDim.x * 256;
  for (; i < n8; i += stride) {
    float s0[8] = {0.f, 0.f, 0.f, 0.f, 0.f, 0.f, 0.f, 0.f};
#pragma unroll
    for (int z = 0; z < 8; ++z) {
      u16x8 a = *(const u16x8*)(p + (size_t)z * zs + (size_t)i * 8);
#pragma unroll
      for (int j = 0; j < 8; ++j) s0[j] += h2f(a[j]);
    }
    u16x8 o;
#pragma unroll
    for (int j = 0; j < 8; ++j) o[j] = f2h_u(s0[j]);
    *(u16x8*)(out + (size_t)i * 8) = o;
  }
}

// ---------------------------------------------------------------------------
// out_f32[i] = sum of 3 f16 partial slices (n8 = n/8 groups of 8)
// ---------------------------------------------------------------------------
__global__ __launch_bounds__(256) void reduce_add3_h_f32(
    const u16* __restrict__ p, float* __restrict__ out, int n8, long zs)
{
  int i = blockIdx.x * 256 + threadIdx.x;
  int stride = gridDim.x * 256;
  for (; i < n8; i += stride) {
    u16x8 a0 = *(const u16x8*)(p + (size_t)i * 8);
    u16x8 a1 = *(const u16x8*)(p + zs + (size_t)i * 8);
    u16x8 a2 = *(const u16x8*)(p + 2 * zs + (size_t)i * 8);
    f32x4 o0, o1;
#pragma unroll
    for (int j = 0; j < 4; ++j) {
      o0[j] = h2f(a0[j]) + h2f(a1[j]) + h2f(a2[j]);
      o1[j] = h2f(a0[4 + j]) + h2f(a1[4 + j]) + h2f(a2[4 + j]);
    }
    *(f32x4*)(out + (size_t)i * 8) = o0;
    *(f32x4*)(out + (size_t)i * 8 + 4) = o1;
  }
}

// ---------------------------------------------------------------------------
// Per-(t, head) RMSNorm(*w) + RoPE for Q (f16 in place; w, freqs f32).
// ---------------------------------------------------------------------------
__global__ __launch_bounds__(64) void norm_rope_q(
    u16* __restrict__ q, const float* __restrict__ w,
    const float* __restrict__ fc, const float* __restrict__ fs)
{
  int t = blockIdx.x, h = blockIdx.y, lane = threadIdx.x;
  u16* row = q + (size_t)t * 16384 + h * 512;
  u16x8 v = *(const u16x8*)(row + lane * 8);
  float x[8];
  float ss = 0.f;
#pragma unroll
  for (int j = 0; j < 8; ++j) { x[j] = h2f(v[j]); ss += x[j] * x[j]; }
#pragma unroll
  for (int m = 1; m < 64; m <<= 1) ss += __shfl_xor(ss, m, 64);
  float rms = rsqrtf(ss * (1.f / 512.f) + 1e-6f);
  f32x4 w0 = *(const f32x4*)(w + lane * 8);
  f32x4 w1 = *(const f32x4*)(w + lane * 8 + 4);
  float y[8];
#pragma unroll
  for (int j = 0; j < 4; ++j) {
    y[j] = x[j] * rms * w0[j];
    y[4 + j] = x[4 + j] * rms * w1[j];
  }
  if (lane < 16) {
    f32x4 cv = *(const f32x4*)(fc + t * 64 + lane * 4);
    f32x4 sv = *(const f32x4*)(fs + t * 64 + lane * 4);
#pragma unroll
    for (int j = 0; j < 4; ++j) {
      float c = cv[j], s = sv[j];
      float a = y[2 * j], b = y[2 * j + 1];
      y[2 * j] = a * c - b * s;
      y[2 * j + 1] = a * s + b * c;
    }
  }
  u16x8 o;
#pragma unroll
  for (int j = 0; j < 8; ++j) o[j] = f2h_u(y[j]);
  *(u16x8*)(row + lane * 8) = o;
}

// ---------------------------------------------------------------------------
// Per-(t, kv): shared sumsq; k = rms*k_w + RoPE (in place), v = rms (-> vout).
// ---------------------------------------------------------------------------
__global__ __launch_bounds__(64) void norm_kv(
    u16* __restrict__ kraw, u16* __restrict__ vout, const float* __restrict__ kw,
    const float* __restrict__ fc, const float* __restrict__ fs)
{
  int t = blockIdx.x, kv = blockIdx.y, lane = threadIdx.x;
  u16* row  = kraw + (size_t)t * 2048 + kv * 512;
  u16* vrow = vout + (size_t)t * 2048 + kv * 512;
  u16x8 v = *(const u16x8*)(row + lane * 8);
  float x[8];
  float ss = 0.f;
#pragma unroll
  for (int j = 0; j < 8; ++j) { x[j] = h2f(v[j]); ss += x[j] * x[j]; }
#pragma unroll
  for (int m = 1; m < 64; m <<= 1) ss += __shfl_xor(ss, m, 64);
  float rms = rsqrtf(ss * (1.f / 512.f) + 1e-6f);
  f32x4 w0 = *(const f32x4*)(kw + lane * 8);
  f32x4 w1 = *(const f32x4*)(kw + lane * 8 + 4);
  float yk[8], yv[8];
#pragma unroll
  for (int j = 0; j < 4; ++j) {
    yv[j] = x[j] * rms;           yv[4 + j] = x[4 + j] * rms;
    yk[j] = yv[j] * w0[j];        yk[4 + j] = yv[4 + j] * w1[j];
  }
  if (lane < 16) {
    f32x4 cv = *(const f32x4*)(fc + t * 64 + lane * 4);
    f32x4 sv = *(const f32x4*)(fs + t * 64 + lane * 4);
#pragma unroll
    for (int j = 0; j < 4; ++j) {
      float c = cv[j], s = sv[j];
      float a = yk[2 * j], b = yk[2 * j + 1];
      yk[2 * j] = a * c - b * s;
      yk[2 * j + 1] = a * s + b * c;
    }
  }
  u16x8 ok, ov;
#pragma unroll
  for (int j = 0; j < 8; ++j) { ok[j] = f2h_u(yk[j]); ov[j] = f2h_u(yv[j]); }
  *(u16x8*)(row + lane * 8) = ok;
  *(u16x8*)(vrow + lane * 8) = ov;
}

// ---------------------------------------------------------------------------
// Flash attention v2: 4-wave block, 32 q-rows, D=512 split 4x128 across waves.
// ---------------------------------------------------------------------------
__global__ __launch_bounds__(256) void attn2_kernel(
    const u16* __restrict__ Q, const u16* __restrict__ Kb,
    const u16* __restrict__ Vt, u16* __restrict__ Y)
{
  __shared__ float Sred[4 * 32 * 68];
  __shared__ u16 Plds[32 * 64];
  __shared__ float scf[32];
  __shared__ float linv[32];
  __shared__ int nf[4];

  int h = blockIdx.x;
  int qtb = 31 - blockIdx.y;
  int kv = h >> 3;
  int tid = threadIdx.x;
  int lane = tid & 63;
  int w = tid >> 6;
  int r15 = lane & 15, g = lane >> 4;
  int qbase = qtb * 32;
  int dbase = w * 128;

  int jloc = lane >> 3, cl = lane & 7;
  int jrow = w * 8 + jloc;
  int qr_sm = qbase + jrow;

  f16x8 qf[2][4];
  {
    const u16* qp = Q + (size_t)(qbase + r15) * 16384 + h * 512 + dbase + g * 8;
#pragma unroll
    for (int mi = 0; mi < 2; ++mi)
#pragma unroll
      for (int ks = 0; ks < 4; ++ks)
        qf[mi][ks] = ld_h8(qp + (size_t)mi * 16 * 16384 + ks * 32);
  }

  f32x4 acc[2][8];
#pragma unroll
  for (int mi = 0; mi < 2; ++mi)
#pragma unroll
    for (int nt = 0; nt < 8; ++nt) acc[mi][nt] = (f32x4){0.f, 0.f, 0.f, 0.f};
  float m_ = -1e30f, l_ = 0.f;

  const u16* kp_base = Kb + kv * 512 + dbase;
  const u16* vt_base = Vt + (size_t)kv * (512 * 1024) + (size_t)dbase * 1024;
  int nst = (qbase + 31) / 64 + 1;

  for (int st = 0; st < nst; ++st) {
    int s0 = st * 64;
    f32x4 sa[2][4];
#pragma unroll
    for (int mi = 0; mi < 2; ++mi)
#pragma unroll
      for (int nt = 0; nt < 4; ++nt) sa[mi][nt] = (f32x4){0.f, 0.f, 0.f, 0.f};
#pragma unroll
    for (int ks = 0; ks < 4; ++ks) {
#pragma unroll
      for (int nt = 0; nt < 4; ++nt) {
        f16x8 kf = ld_h8(kp_base + (size_t)(s0 + nt * 16 + r15) * 2048 + ks * 32 + g * 8);
#pragma unroll
        for (int mi = 0; mi < 2; ++mi)
          sa[mi][nt] = MFMA16(qf[mi][ks], kf, sa[mi][nt]);
      }
    }
    {
      float* sw = Sred + w * 32 * 68;
#pragma unroll
      for (int mi = 0; mi < 2; ++mi)
#pragma unroll
        for (int nt = 0; nt < 4; ++nt)
#pragma unroll
          for (int r = 0; r < 4; ++r)
            sw[(mi * 16 + g * 4 + r) * 68 + nt * 16 + r15] = sa[mi][nt][r];
    }
    __syncthreads();

    {
      const float* sp = Sred + jrow * 68 + cl * 8;
      f32x4 a0 = *(const f32x4*)(sp);
      f32x4 a1 = *(const f32x4*)(sp + 4);
#pragma unroll
      for (int p = 1; p < 4; ++p) {
        a0 += *(const f32x4*)(sp + p * 32 * 68);
        a1 += *(const f32x4*)(sp + p * 32 * 68 + 4);
      }
      float sv[8];
      int sbase = s0 + cl * 8;
#pragma unroll
      for (int j = 0; j < 4; ++j) {
        sv[j]     = (sbase + j     <= qr_sm) ? a0[j] : -1e30f;
        sv[4 + j] = (sbase + 4 + j <= qr_sm) ? a1[j] : -1e30f;
      }
      float mm = sv[0];
#pragma unroll
      for (int j = 1; j < 8; ++j) mm = fmaxf(mm, sv[j]);
      mm = fmaxf(mm, __shfl_xor(mm, 1, 64));
      mm = fmaxf(mm, __shfl_xor(mm, 2, 64));
      mm = fmaxf(mm, __shfl_xor(mm, 4, 64));
      bool defer = (mm <= m_ + 8.f);
      float sc;
      if (defer) { sc = 1.f; }
      else { float mn = fmaxf(m_, mm); sc = __expf(m_ - mn); m_ = mn; }
      float pv8[8], rsum = 0.f;
#pragma unroll
      for (int j = 0; j < 8; ++j) { pv8[j] = __expf(sv[j] - m_); rsum += pv8[j]; }
      rsum += __shfl_xor(rsum, 1, 64);
      rsum += __shfl_xor(rsum, 2, 64);
      rsum += __shfl_xor(rsum, 4, 64);
      l_ = l_ * sc + rsum;
      u16x8 pw;
#pragma unroll
      for (int j = 0; j < 8; ++j) pw[j] = f2h_u(pv8[j]);
      *(u16x8*)(Plds + jrow * 64 + ((cl ^ (jrow & 7)) * 8)) = pw;
      if (cl == 0) scf[jrow] = sc;
      int need = __any((int)(!defer));
      if (lane == 0) nf[w] = need;
    }
    __syncthreads();

    if (nf[0] | nf[1] | nf[2] | nf[3]) {
#pragma unroll
      for (int mi = 0; mi < 2; ++mi)
#pragma unroll
        for (int r = 0; r < 4; ++r) {
          float s = scf[mi * 16 + g * 4 + r];
#pragma unroll
          for (int nt = 0; nt < 8; ++nt) acc[mi][nt][r] *= s;
        }
    }
    f16x8 pa[2][2];
#pragma unroll
    for (int mi = 0; mi < 2; ++mi)
#pragma unroll
      for (int ks = 0; ks < 2; ++ks) {
        int row = mi * 16 + r15;
        int c = ks * 4 + g;
        pa[mi][ks] = ld_h8(Plds + row * 64 + ((c ^ (row & 7)) * 8));
      }
#pragma unroll
    for (int ks = 0; ks < 2; ++ks)
#pragma unroll
      for (int nt = 0; nt < 8; ++nt) {
        f16x8 vf = ld_h8(vt_base + (size_t)(nt * 16 + r15) * 1024 + s0 + ks * 32 + g * 8);
#pragma unroll
        for (int mi = 0; mi < 2; ++mi)
          acc[mi][nt] = MFMA16(pa[mi][ks], vf, acc[mi][nt]);
      }
  }

  if (cl == 0) linv[jrow] = 1.0f / l_;
  __syncthreads();
#pragma unroll
  for (int mi = 0; mi < 2; ++mi)
#pragma unroll
    for (int r = 0; r < 4; ++r) {
      int row = mi * 16 + g * 4 + r;
      float li = linv[row];
      u16* yp = Y + (size_t)(qbase + row) * 16384 + h * 512 + dbase + r15;
#pragma unroll
      for (int nt = 0; nt < 8; ++nt)
        yp[nt * 16] = f2h_u(acc[mi][nt][r] * li);
    }
}

// ---------------------------------------------------------------------------
extern "C" void kernel_launch(void* const* d_in, const int* in_sizes, int n_in,
                              void* d_out, int out_size, void* d_ws, size_t ws_size,
                              hipStream_t stream)
{
  const float* x  = (const float*)d_in[0];
  const float* wq = (const float*)d_in[3];
  const float* wk = (const float*)d_in[4];
  const float* wo = (const float*)d_in[5];
  const float* qw = (const float*)d_in[6];
  const float* kw = (const float*)d_in[7];
  const float* fc = (const float*)d_in[10];
  const float* fs = (const float*)d_in[11];
  float* out = (float*)d_out;
  char* ws = (char*)d_ws;

  // ws layout (bytes):
  u16* Qbuf = (u16*)(ws + 0);            // [1024][16384] f16  32 MiB
  u16* Kbuf = (u16*)(ws + 33554432);     // [1024][2048]  f16   4 MiB
  u16* Vbuf = (u16*)(ws + 37748736);     // [1024][2048]  f16   4 MiB
  u16* Vt   = (u16*)(ws + 41943040);     // [4][512][1024] f16  4 MiB
  u16* Ybuf = (u16*)(ws + 46137344);     // [1024][16384] f16  32 MiB
  u16* xh   = (u16*)(ws + 79691776);     // [1024][5376]  f16  ~10.5 MiB
  // Split-K partials: wo uses Qbuf region (dead after attention) as 3x f16
  // slices; wk uses Ybuf region (dead until attention) as 8x f16 slices.
  u16* PbH  = (u16*)ws;                  // 3 x [1024][5376] f16 = 31.5 MiB
  u16* PbK  = (u16*)(ws + 46137344);     // 8 x [1024][2048] f16 = 32 MiB

  // 0) x -> f16
  convert_f32_f16<<<672, 256, 0, stream>>>(x, xh, (1024 * 5376) / 8);

  // 1) Q = x @ wq  (fused W-transpose GEMM, f16 out, bxfast: A-panel L2-fits)
  gemm_ktn<false><<<dim3(128, 4, 1), 512, 0, stream>>>(
      xh, wq, (void*)Qbuf, 5376, 5376, 1, 5376, 16384, 16384, 0L);

  // 2) Kraw = x @ wk : split-K x8 (f16 partials into PbK), reduce -> Kbuf f16
  gemm_ktn<false><<<dim3(16, 4, 8), 512, 0, stream>>>(
      xh, wk, (void*)PbK, 672, 5376, 1, 5376, 2048, 2048, 2097152L);
  reduce_add8_h_f16<<<1024, 256, 0, stream>>>(PbK, Kbuf, 262144, 2097152L);

  // 3) norms + rope
  norm_rope_q<<<dim3(1024, 32), 64, 0, stream>>>(Qbuf, qw, fc, fs);
  norm_kv<<<dim3(1024, 4), 64, 0, stream>>>(Kbuf, Vbuf, kw, fc, fs);
  // 4) Vt[kv][d][t] = V^T
  transpose_h16<<<dim3(8, 16, 4), 256, 0, stream>>>(
      Vbuf, Vt, 1024, 512, 2048, 1024, 512L, 524288L);
  // 5) attention -> Ybuf [t][h*512+d]
  attn2_kernel<<<dim3(32, 32), 256, 0, stream>>>(Qbuf, Kbuf, Vt, Ybuf);

  // 6) out = Y @ wo : split-K x3 (f16 partials into PbH, non-uniform
  //    171/171/170 K-steps via Ktot clamp; A-panel 8MB > L2 -> bxfast=0),
  //    reduce -> out f32
  gemm_ktn<false><<<dim3(42, 4, 3), 512, 0, stream>>>(
      Ybuf, wo, (void*)PbH, 5472, 16384, 0, 16384, 5376, 5376, 5505024L);
  reduce_add3_h_f32<<<2048, 256, 0, stream>>>(PbH, out, 688128, 5505024L);
}

// Round 16
// 748.059 us; speedup vs baseline: 4.2119x; 1.0085x over previous
//
#include <hip/hip_runtime.h>
#include <stdint.h>

typedef unsigned short u16;
typedef _Float16 f16;
typedef f16 f16x8 __attribute__((ext_vector_type(8)));
typedef float f32x4 __attribute__((ext_vector_type(4)));
typedef unsigned short u16x4 __attribute__((ext_vector_type(4)));
typedef unsigned short u16x8 __attribute__((ext_vector_type(8)));

#define MFMA16(a, b, c) __builtin_amdgcn_mfma_f32_16x16x32_f16(a, b, c, 0, 0, 0)

__device__ __forceinline__ u16 f2h_u(float f) {
  union { f16 h; u16 u; } v; v.h = (f16)f; return v.u;
}
__device__ __forceinline__ float h2f(u16 u) {
  union { u16 u; f16 h; } v; v.u = u; return (float)v.h;
}
__device__ __forceinline__ f16x8 ld_h8(const u16* p) {
  return *(const f16x8*)p;
}
// async global->LDS, 16B per lane; LDS dest = wave-uniform base + lane*16
__device__ __forceinline__ void gl_lds16(const u16* g, u16* l) {
  __builtin_amdgcn_global_load_lds(
      (const __attribute__((address_space(1))) void*)g,
      (__attribute__((address_space(3))) void*)l, 16, 0, 0);
}

// ---------------------------------------------------------------------------
// f32 -> f16 elementwise convert (n8 = n/8 groups of 8)
// ---------------------------------------------------------------------------
__global__ __launch_bounds__(256) void convert_f32_f16(
    const float* __restrict__ in, u16* __restrict__ out, int n8)
{
  int i = blockIdx.x * 256 + threadIdx.x;
  int stride = gridDim.x * 256;
  for (; i < n8; i += stride) {
    f32x4 a = *(const f32x4*)(in + (size_t)i * 8);
    f32x4 b = *(const f32x4*)(in + (size_t)i * 8 + 4);
    u16x8 o;
#pragma unroll
    for (int j = 0; j < 4; ++j) { o[j] = f2h_u(a[j]); o[4 + j] = f2h_u(b[j]); }
    *(u16x8*)(out + (size_t)i * 8) = o;
  }
}

// ---------------------------------------------------------------------------
// f16-bits transpose (for V^T). Grid: (C/64, R/64, Z).
// ---------------------------------------------------------------------------
__global__ __launch_bounds__(256) void transpose_h16(
    const u16* __restrict__ in, u16* __restrict__ out,
    int R, int C, int ldi, int ldo, long zin, long zout)
{
  __shared__ u16 tile[64 * 66];
  const u16* ip = in + (size_t)blockIdx.z * zin;
  u16* op = out + (size_t)blockIdx.z * zout;
  int x0 = blockIdx.x * 64, y0 = blockIdx.y * 64;
  int t = threadIdx.x;
  int xr = (t & 15) * 4;
  int yr = t >> 4;
#pragma unroll
  for (int p = 0; p < 4; ++p) {
    int y = yr + p * 16;
    u16x4 v = *(const u16x4*)(ip + (size_t)(y0 + y) * ldi + x0 + xr);
    tile[y * 66 + xr + 0] = v.x;
    tile[y * 66 + xr + 1] = v.y;
    tile[y * 66 + xr + 2] = v.z;
    tile[y * 66 + xr + 3] = v.w;
  }
  __syncthreads();
#pragma unroll
  for (int p = 0; p < 4; ++p) {
    int x = (t >> 4) + p * 16;
    int yq = (t & 15) * 4;
    u16x4 v;
    v.x = tile[(yq + 0) * 66 + x];
    v.y = tile[(yq + 1) * 66 + x];
    v.z = tile[(yq + 2) * 66 + x];
    v.w = tile[(yq + 3) * 66 + x];
    *(u16x4*)(op + (size_t)(x0 + x) * ldo + y0 + yq) = v;
  }
}

// ---------------------------------------------------------------------------
// GEMM v6b (fused weight transpose): C[M][N] = A[M][K](f16) * W[K][N](f32).
// 256x128 tile, 8 waves, BK=32, 3 LDS buffers. A staged via gl_lds16
// (src-XOR-swizzled); B reg-staged: 8 coalesced f32 column loads -> f16x8 ->
// ds_write_b128 at chunk kc^((c>>1)&3). Single-barrier pipeline, counted
// vmcnt: queue at wait = [A(k+1) x2, B(k+1) x8, A(k+2) x2] -> vmcnt(2).
// Ktot clamps K for non-uniform split-K. bxfast=0 (by-fastest) is correct
// when W >> A: co-XCD blocks share one W col-panel (4x L2 reuse on the big
// operand; A is L3-resident). [r15 falsified bxfast=1: FETCH 215->700 MB]
// Grid: (N/128, M/256, nz); split-K via blockIdx.z, partials at z*zstride.
// ---------------------------------------------------------------------------
template <bool F32OUT>
__global__ __launch_bounds__(512, 4) void gemm_ktn(
    const u16* __restrict__ A, const float* __restrict__ W, void* __restrict__ Cv,
    int Ksp, int Ktot, int bxfast, int lda, int ldw, int ldc, long zstride)
{
  __shared__ alignas(16) u16 As[3 * 256 * 32];   // 3 x 16 KB
  __shared__ alignas(16) u16 Bs[3 * 128 * 32];   // 3 x  8 KB
  int tid = threadIdx.x;
  int lane = tid & 63;
  int wave = tid >> 6;
  int wm = wave >> 2, wn = wave & 3;
  int r15 = lane & 15, g = lane >> 4;

  // XCD-bijective swizzle + supertile decomposition (bxfast selects order)
  int gx = gridDim.x, gy = gridDim.y;
  int nwg = gx * gy;
  int flat = blockIdx.y * gx + blockIdx.x;
  int q = nwg >> 3, rr = nwg & 7, xcd = flat & 7, lo = flat >> 3;
  int s = ((xcd < rr) ? xcd * (q + 1) : rr * (q + 1) + (xcd - rr) * q) + lo;
  int by, bx;
  if (bxfast) { bx = s % gx; by = s / gx; }
  else        { by = s % gy; bx = s / gy; }
  int row0 = by * 256, col0 = bx * 128;
  int kbeg = blockIdx.z * Ksp;
  int krem = Ktot - kbeg;
  int klen = (krem < Ksp) ? krem : Ksp;

  // A staging: lane covers LDS row tid>>2, 16B chunk tid&3, src XOR-swizzled
  int rA = tid >> 2;
  int pc = tid & 3;
  int cs = pc ^ ((rA >> 1) & 3);
  const u16* Ag0 = A + (size_t)(row0 + rA) * lda + kbeg + cs * 8;  // rows 0..127
  const u16* Ag1 = Ag0 + (size_t)128 * lda;                        // rows 128..255

  // B staging: col cB (coalesced across lanes), k-chunk kc (8 k each)
  int cB = tid & 127;
  int kc = tid >> 7;
  const float* Wg = W + (size_t)(kbeg + kc * 8) * ldw + col0 + cB;
  int bwoff = cB * 32 + ((kc ^ ((cB >> 1) & 3)) * 8);  // u16 units

  f32x4 acc[8][2];
#pragma unroll
  for (int i = 0; i < 8; ++i)
#pragma unroll
    for (int j = 0; j < 2; ++j) acc[i][j] = (f32x4){0.f, 0.f, 0.f, 0.f};

  int nk = klen >> 5;
  float bw[8];

  auto BLOAD = [&](int kk) {          // tile kk's 8 column f32 loads
#pragma unroll
    for (int j = 0; j < 8; ++j)
      bw[j] = Wg[(size_t)(kk * 32 + j) * ldw];
  };
  auto BWRITE = [&](int b) {          // convert + swizzled ds_write_b128
    u16x8 o;
#pragma unroll
    for (int j = 0; j < 8; ++j) o[j] = f2h_u(bw[j]);
    *(u16x8*)(Bs + b * 4096 + bwoff) = o;
  };
  auto STAGE_A = [&](int kk, int b) {
    u16* la = As + b * 8192 + wave * 512;
    gl_lds16(Ag0 + (size_t)kk * 32, la);
    gl_lds16(Ag1 + (size_t)kk * 32, la + 4096);
  };

  // prologue: B0 + A0 + A1 issued; confirm B0+A0 (A1 stays in flight)
  BLOAD(0);
  STAGE_A(0, 0);
  if (nk > 1) STAGE_A(1, 1);
  asm volatile("s_waitcnt vmcnt(2)" ::: "memory");
  BWRITE(0);
  asm volatile("s_waitcnt lgkmcnt(0)" ::: "memory");
  __builtin_amdgcn_s_barrier();

  int swz = (g ^ ((r15 >> 1) & 3)) * 8;
  int b0 = 0;
  for (int k = 0; k < nk; ++k) {
    const u16* Ab = As + b0 * 8192;
    const u16* Bb = Bs + b0 * 4096;
    // issue long-latency loads first
    if (k + 1 < nk) BLOAD(k + 1);
    if (k + 2 < nk) {
      int b2 = b0 + 2; if (b2 >= 3) b2 -= 3;
      STAGE_A(k + 2, b2);
    }
    // frag reads for tile k (published by previous barrier)
    f16x8 bfr[2], af[4];
#pragma unroll
    for (int ni = 0; ni < 2; ++ni)
      bfr[ni] = ld_h8(Bb + (wn * 32 + ni * 16 + r15) * 32 + swz);
#pragma unroll
    for (int m2 = 0; m2 < 4; ++m2)
      af[m2] = ld_h8(Ab + (wm * 128 + m2 * 16 + r15) * 32 + swz);
    __builtin_amdgcn_s_setprio(1);
#pragma unroll
    for (int m2 = 0; m2 < 4; ++m2)
#pragma unroll
      for (int ni = 0; ni < 2; ++ni)
        acc[m2][ni] = MFMA16(af[m2], bfr[ni], acc[m2][ni]);
    f16x8 ag[4];
#pragma unroll
    for (int m2 = 0; m2 < 4; ++m2)
      ag[m2] = ld_h8(Ab + (wm * 128 + (4 + m2) * 16 + r15) * 32 + swz);
#pragma unroll
    for (int m2 = 0; m2 < 4; ++m2)
#pragma unroll
      for (int ni = 0; ni < 2; ++ni)
        acc[4 + m2][ni] = MFMA16(ag[m2], bfr[ni], acc[4 + m2][ni]);
    __builtin_amdgcn_s_setprio(0);
    // confirm A(k+1)+B(k+1); leave A(k+2) in flight; write B(k+1) to its buf
    if (k + 1 < nk) {
      if (k + 2 < nk) {
        asm volatile("s_waitcnt vmcnt(2)" ::: "memory");
      } else {
        asm volatile("s_waitcnt vmcnt(0)" ::: "memory");
      }
      int b1 = b0 + 1; if (b1 >= 3) b1 -= 3;
      BWRITE(b1);
    }
    asm volatile("s_waitcnt lgkmcnt(0)" ::: "memory");
    __builtin_amdgcn_s_barrier();   // publishes tile k+1 (A DMA + B ds_write)
    b0 = (b0 == 2) ? 0 : b0 + 1;
  }

  // C/D layout: col = lane&15, row = (lane>>4)*4 + reg
#pragma unroll
  for (int mi = 0; mi < 8; ++mi)
#pragma unroll
    for (int ni = 0; ni < 2; ++ni) {
      int row = row0 + wm * 128 + mi * 16 + g * 4;
      int col = col0 + wn * 32 + ni * 16 + r15;
#pragma unroll
      for (int r = 0; r < 4; ++r) {
        if constexpr (F32OUT)
          ((float*)Cv)[(size_t)blockIdx.z * zstride + (size_t)(row + r) * ldc + col] = acc[mi][ni][r];
        else
          ((u16*)Cv)[(size_t)blockIdx.z * zstride + (size_t)(row + r) * ldc + col] = f2h_u(acc[mi][ni][r]);
      }
    }
}

// ---------------------------------------------------------------------------
// out_f16[i] = sum of 8 f16 partial slices (n8 = n/8 groups of 8)
// ---------------------------------------------------------------------------
__global__ __launch_bounds__(256) void reduce_add8_h_f16(
    const u16* __restrict__ p, u16* __restrict__ out, int n8, long zs)
{
  int i = blockIdx.x * 256 + threadIdx.x;
  int stride = gridDim.x * 256;
  for (; i < n8; i += stride) {
    float s0[8] = {0.f, 0.f, 0.f, 0.f, 0.f, 0.f, 0.f, 0.f};
#pragma unroll
    for (int z = 0; z < 8; ++z) {
      u16x8 a = *(const u16x8*)(p + (size_t)z * zs + (size_t)i * 8);
#pragma unroll
      for (int j = 0; j < 8; ++j) s0[j] += h2f(a[j]);
    }
    u16x8 o;
#pragma unroll
    for (int j = 0; j < 8; ++j) o[j] = f2h_u(s0[j]);
    *(u16x8*)(out + (size_t)i * 8) = o;
  }
}

// ---------------------------------------------------------------------------
// out_f32[i] = sum of 3 f16 partial slices (n8 = n/8 groups of 8)
// ---------------------------------------------------------------------------
__global__ __launch_bounds__(256) void reduce_add3_h_f32(
    const u16* __restrict__ p, float* __restrict__ out, int n8, long zs)
{
  int i = blockIdx.x * 256 + threadIdx.x;
  int stride = gridDim.x * 256;
  for (; i < n8; i += stride) {
    u16x8 a0 = *(const u16x8*)(p + (size_t)i * 8);
    u16x8 a1 = *(const u16x8*)(p + zs + (size_t)i * 8);
    u16x8 a2 = *(const u16x8*)(p + 2 * zs + (size_t)i * 8);
    f32x4 o0, o1;
#pragma unroll
    for (int j = 0; j < 4; ++j) {
      o0[j] = h2f(a0[j]) + h2f(a1[j]) + h2f(a2[j]);
      o1[j] = h2f(a0[4 + j]) + h2f(a1[4 + j]) + h2f(a2[4 + j]);
    }
    *(f32x4*)(out + (size_t)i * 8) = o0;
    *(f32x4*)(out + (size_t)i * 8 + 4) = o1;
  }
}

// ---------------------------------------------------------------------------
// Per-(t, head) RMSNorm(*w) + RoPE for Q (f16 in place; w, freqs f32).
// ---------------------------------------------------------------------------
__global__ __launch_bounds__(64) void norm_rope_q(
    u16* __restrict__ q, const float* __restrict__ w,
    const float* __restrict__ fc, const float* __restrict__ fs)
{
  int t = blockIdx.x, h = blockIdx.y, lane = threadIdx.x;
  u16* row = q + (size_t)t * 16384 + h * 512;
  u16x8 v = *(const u16x8*)(row + lane * 8);
  float x[8];
  float ss = 0.f;
#pragma unroll
  for (int j = 0; j < 8; ++j) { x[j] = h2f(v[j]); ss += x[j] * x[j]; }
#pragma unroll
  for (int m = 1; m < 64; m <<= 1) ss += __shfl_xor(ss, m, 64);
  float rms = rsqrtf(ss * (1.f / 512.f) + 1e-6f);
  f32x4 w0 = *(const f32x4*)(w + lane * 8);
  f32x4 w1 = *(const f32x4*)(w + lane * 8 + 4);
  float y[8];
#pragma unroll
  for (int j = 0; j < 4; ++j) {
    y[j] = x[j] * rms * w0[j];
    y[4 + j] = x[4 + j] * rms * w1[j];
  }
  if (lane < 16) {
    f32x4 cv = *(const f32x4*)(fc + t * 64 + lane * 4);
    f32x4 sv = *(const f32x4*)(fs + t * 64 + lane * 4);
#pragma unroll
    for (int j = 0; j < 4; ++j) {
      float c = cv[j], s = sv[j];
      float a = y[2 * j], b = y[2 * j + 1];
      y[2 * j] = a * c - b * s;
      y[2 * j + 1] = a * s + b * c;
    }
  }
  u16x8 o;
#pragma unroll
  for (int j = 0; j < 8; ++j) o[j] = f2h_u(y[j]);
  *(u16x8*)(row + lane * 8) = o;
}

// ---------------------------------------------------------------------------
// Per-(t, kv): shared sumsq; k = rms*k_w + RoPE (in place), v = rms (-> vout).
// ---------------------------------------------------------------------------
__global__ __launch_bounds__(64) void norm_kv(
    u16* __restrict__ kraw, u16* __restrict__ vout, const float* __restrict__ kw,
    const float* __restrict__ fc, const float* __restrict__ fs)
{
  int t = blockIdx.x, kv = blockIdx.y, lane = threadIdx.x;
  u16* row  = kraw + (size_t)t * 2048 + kv * 512;
  u16* vrow = vout + (size_t)t * 2048 + kv * 512;
  u16x8 v = *(const u16x8*)(row + lane * 8);
  float x[8];
  float ss = 0.f;
#pragma unroll
  for (int j = 0; j < 8; ++j) { x[j] = h2f(v[j]); ss += x[j] * x[j]; }
#pragma unroll
  for (int m = 1; m < 64; m <<= 1) ss += __shfl_xor(ss, m, 64);
  float rms = rsqrtf(ss * (1.f / 512.f) + 1e-6f);
  f32x4 w0 = *(const f32x4*)(kw + lane * 8);
  f32x4 w1 = *(const f32x4*)(kw + lane * 8 + 4);
  float yk[8], yv[8];
#pragma unroll
  for (int j = 0; j < 4; ++j) {
    yv[j] = x[j] * rms;           yv[4 + j] = x[4 + j] * rms;
    yk[j] = yv[j] * w0[j];        yk[4 + j] = yv[4 + j] * w1[j];
  }
  if (lane < 16) {
    f32x4 cv = *(const f32x4*)(fc + t * 64 + lane * 4);
    f32x4 sv = *(const f32x4*)(fs + t * 64 + lane * 4);
#pragma unroll
    for (int j = 0; j < 4; ++j) {
      float c = cv[j], s = sv[j];
      float a = yk[2 * j], b = yk[2 * j + 1];
      yk[2 * j] = a * c - b * s;
      yk[2 * j + 1] = a * s + b * c;
    }
  }
  u16x8 ok, ov;
#pragma unroll
  for (int j = 0; j < 8; ++j) { ok[j] = f2h_u(yk[j]); ov[j] = f2h_u(yv[j]); }
  *(u16x8*)(row + lane * 8) = ok;
  *(u16x8*)(vrow + lane * 8) = ov;
}

// ---------------------------------------------------------------------------
// Flash attention v2: 4-wave block, 32 q-rows, D=512 split 4x128 across waves.
// ---------------------------------------------------------------------------
__global__ __launch_bounds__(256) void attn2_kernel(
    const u16* __restrict__ Q, const u16* __restrict__ Kb,
    const u16* __restrict__ Vt, u16* __restrict__ Y)
{
  __shared__ float Sred[4 * 32 * 68];
  __shared__ u16 Plds[32 * 64];
  __shared__ float scf[32];
  __shared__ float linv[32];
  __shared__ int nf[4];

  int h = blockIdx.x;
  int qtb = 31 - blockIdx.y;
  int kv = h >> 3;
  int tid = threadIdx.x;
  int lane = tid & 63;
  int w = tid >> 6;
  int r15 = lane & 15, g = lane >> 4;
  int qbase = qtb * 32;
  int dbase = w * 128;

  int jloc = lane >> 3, cl = lane & 7;
  int jrow = w * 8 + jloc;
  int qr_sm = qbase + jrow;

  f16x8 qf[2][4];
  {
    const u16* qp = Q + (size_t)(qbase + r15) * 16384 + h * 512 + dbase + g * 8;
#pragma unroll
    for (int mi = 0; mi < 2; ++mi)
#pragma unroll
      for (int ks = 0; ks < 4; ++ks)
        qf[mi][ks] = ld_h8(qp + (size_t)mi * 16 * 16384 + ks * 32);
  }

  f32x4 acc[2][8];
#pragma unroll
  for (int mi = 0; mi < 2; ++mi)
#pragma unroll
    for (int nt = 0; nt < 8; ++nt) acc[mi][nt] = (f32x4){0.f, 0.f, 0.f, 0.f};
  float m_ = -1e30f, l_ = 0.f;

  const u16* kp_base = Kb + kv * 512 + dbase;
  const u16* vt_base = Vt + (size_t)kv * (512 * 1024) + (size_t)dbase * 1024;
  int nst = (qbase + 31) / 64 + 1;

  for (int st = 0; st < nst; ++st) {
    int s0 = st * 64;
    f32x4 sa[2][4];
#pragma unroll
    for (int mi = 0; mi < 2; ++mi)
#pragma unroll
      for (int nt = 0; nt < 4; ++nt) sa[mi][nt] = (f32x4){0.f, 0.f, 0.f, 0.f};
#pragma unroll
    for (int ks = 0; ks < 4; ++ks) {
#pragma unroll
      for (int nt = 0; nt < 4; ++nt) {
        f16x8 kf = ld_h8(kp_base + (size_t)(s0 + nt * 16 + r15) * 2048 + ks * 32 + g * 8);
#pragma unroll
        for (int mi = 0; mi < 2; ++mi)
          sa[mi][nt] = MFMA16(qf[mi][ks], kf, sa[mi][nt]);
      }
    }
    {
      float* sw = Sred + w * 32 * 68;
#pragma unroll
      for (int mi = 0; mi < 2; ++mi)
#pragma unroll
        for (int nt = 0; nt < 4; ++nt)
#pragma unroll
          for (int r = 0; r < 4; ++r)
            sw[(mi * 16 + g * 4 + r) * 68 + nt * 16 + r15] = sa[mi][nt][r];
    }
    __syncthreads();

    {
      const float* sp = Sred + jrow * 68 + cl * 8;
      f32x4 a0 = *(const f32x4*)(sp);
      f32x4 a1 = *(const f32x4*)(sp + 4);
#pragma unroll
      for (int p = 1; p < 4; ++p) {
        a0 += *(const f32x4*)(sp + p * 32 * 68);
        a1 += *(const f32x4*)(sp + p * 32 * 68 + 4);
      }
      float sv[8];
      int sbase = s0 + cl * 8;
#pragma unroll
      for (int j = 0; j < 4; ++j) {
        sv[j]     = (sbase + j     <= qr_sm) ? a0[j] : -1e30f;
        sv[4 + j] = (sbase + 4 + j <= qr_sm) ? a1[j] : -1e30f;
      }
      float mm = sv[0];
#pragma unroll
      for (int j = 1; j < 8; ++j) mm = fmaxf(mm, sv[j]);
      mm = fmaxf(mm, __shfl_xor(mm, 1, 64));
      mm = fmaxf(mm, __shfl_xor(mm, 2, 64));
      mm = fmaxf(mm, __shfl_xor(mm, 4, 64));
      bool defer = (mm <= m_ + 8.f);
      float sc;
      if (defer) { sc = 1.f; }
      else { float mn = fmaxf(m_, mm); sc = __expf(m_ - mn); m_ = mn; }
      float pv8[8], rsum = 0.f;
#pragma unroll
      for (int j = 0; j < 8; ++j) { pv8[j] = __expf(sv[j] - m_); rsum += pv8[j]; }
      rsum += __shfl_xor(rsum, 1, 64);
      rsum += __shfl_xor(rsum, 2, 64);
      rsum += __shfl_xor(rsum, 4, 64);
      l_ = l_ * sc + rsum;
      u16x8 pw;
#pragma unroll
      for (int j = 0; j < 8; ++j) pw[j] = f2h_u(pv8[j]);
      *(u16x8*)(Plds + jrow * 64 + ((cl ^ (jrow & 7)) * 8)) = pw;
      if (cl == 0) scf[jrow] = sc;
      int need = __any((int)(!defer));
      if (lane == 0) nf[w] = need;
    }
    __syncthreads();

    if (nf[0] | nf[1] | nf[2] | nf[3]) {
#pragma unroll
      for (int mi = 0; mi < 2; ++mi)
#pragma unroll
        for (int r = 0; r < 4; ++r) {
          float s = scf[mi * 16 + g * 4 + r];
#pragma unroll
          for (int nt = 0; nt < 8; ++nt) acc[mi][nt][r] *= s;
        }
    }
    f16x8 pa[2][2];
#pragma unroll
    for (int mi = 0; mi < 2; ++mi)
#pragma unroll
      for (int ks = 0; ks < 2; ++ks) {
        int row = mi * 16 + r15;
        int c = ks * 4 + g;
        pa[mi][ks] = ld_h8(Plds + row * 64 + ((c ^ (row & 7)) * 8));
      }
#pragma unroll
    for (int ks = 0; ks < 2; ++ks)
#pragma unroll
      for (int nt = 0; nt < 8; ++nt) {
        f16x8 vf = ld_h8(vt_base + (size_t)(nt * 16 + r15) * 1024 + s0 + ks * 32 + g * 8);
#pragma unroll
        for (int mi = 0; mi < 2; ++mi)
          acc[mi][nt] = MFMA16(pa[mi][ks], vf, acc[mi][nt]);
      }
  }

  if (cl == 0) linv[jrow] = 1.0f / l_;
  __syncthreads();
#pragma unroll
  for (int mi = 0; mi < 2; ++mi)
#pragma unroll
    for (int r = 0; r < 4; ++r) {
      int row = mi * 16 + g * 4 + r;
      float li = linv[row];
      u16* yp = Y + (size_t)(qbase + row) * 16384 + h * 512 + dbase + r15;
#pragma unroll
      for (int nt = 0; nt < 8; ++nt)
        yp[nt * 16] = f2h_u(acc[mi][nt][r] * li);
    }
}

// ---------------------------------------------------------------------------
extern "C" void kernel_launch(void* const* d_in, const int* in_sizes, int n_in,
                              void* d_out, int out_size, void* d_ws, size_t ws_size,
                              hipStream_t stream)
{
  const float* x  = (const float*)d_in[0];
  const float* wq = (const float*)d_in[3];
  const float* wk = (const float*)d_in[4];
  const float* wo = (const float*)d_in[5];
  const float* qw = (const float*)d_in[6];
  const float* kw = (const float*)d_in[7];
  const float* fc = (const float*)d_in[10];
  const float* fs = (const float*)d_in[11];
  float* out = (float*)d_out;
  char* ws = (char*)d_ws;

  // ws layout (bytes):
  u16* Qbuf = (u16*)(ws + 0);            // [1024][16384] f16  32 MiB
  u16* Kbuf = (u16*)(ws + 33554432);     // [1024][2048]  f16   4 MiB
  u16* Vbuf = (u16*)(ws + 37748736);     // [1024][2048]  f16   4 MiB
  u16* Vt   = (u16*)(ws + 41943040);     // [4][512][1024] f16  4 MiB
  u16* Ybuf = (u16*)(ws + 46137344);     // [1024][16384] f16  32 MiB
  u16* xh   = (u16*)(ws + 79691776);     // [1024][5376]  f16  ~10.5 MiB
  // Split-K partials: wo uses Qbuf region (dead after attention) as 3x f16
  // slices; wk uses Ybuf region (dead until attention) as 8x f16 slices.
  u16* PbH  = (u16*)ws;                  // 3 x [1024][5376] f16 = 31.5 MiB
  u16* PbK  = (u16*)(ws + 46137344);     // 8 x [1024][2048] f16 = 32 MiB

  // 0) x -> f16
  convert_f32_f16<<<672, 256, 0, stream>>>(x, xh, (1024 * 5376) / 8);

  // 1) Q = x @ wq  (fused W-transpose GEMM, f16 out, by-fastest: W L2 reuse)
  gemm_ktn<false><<<dim3(128, 4, 1), 512, 0, stream>>>(
      xh, wq, (void*)Qbuf, 5376, 5376, 0, 5376, 16384, 16384, 0L);

  // 2) Kraw = x @ wk : split-K x8 (f16 partials into PbK), reduce -> Kbuf f16
  gemm_ktn<false><<<dim3(16, 4, 8), 512, 0, stream>>>(
      xh, wk, (void*)PbK, 672, 5376, 0, 5376, 2048, 2048, 2097152L);
  reduce_add8_h_f16<<<1024, 256, 0, stream>>>(PbK, Kbuf, 262144, 2097152L);

  // 3) norms + rope
  norm_rope_q<<<dim3(1024, 32), 64, 0, stream>>>(Qbuf, qw, fc, fs);
  norm_kv<<<dim3(1024, 4), 64, 0, stream>>>(Kbuf, Vbuf, kw, fc, fs);
  // 4) Vt[kv][d][t] = V^T
  transpose_h16<<<dim3(8, 16, 4), 256, 0, stream>>>(
      Vbuf, Vt, 1024, 512, 2048, 1024, 512L, 524288L);
  // 5) attention -> Ybuf [t][h*512+d]
  attn2_kernel<<<dim3(32, 32), 256, 0, stream>>>(Qbuf, Kbuf, Vt, Ybuf);

  // 6) out = Y @ wo : split-K x3 (f16 partials into PbH, non-uniform
  //    171/171/170 K-steps via Ktot clamp), reduce -> out f32
  gemm_ktn<false><<<dim3(42, 4, 3), 512, 0, stream>>>(
      Ybuf, wo, (void*)PbH, 5472, 16384, 0, 16384, 5376, 5376, 5505024L);
  reduce_add3_h_f32<<<2048, 256, 0, stream>>>(PbH, out, 688128, 5505024L);
}

// Round 17
// 731.871 us; speedup vs baseline: 4.3050x; 1.0221x over previous
//
#include <hip/hip_runtime.h>
#include <stdint.h>

typedef unsigned short u16;
typedef _Float16 f16;
typedef f16 f16x8 __attribute__((ext_vector_type(8)));
typedef float f32x4 __attribute__((ext_vector_type(4)));
typedef unsigned short u16x4 __attribute__((ext_vector_type(4)));
typedef unsigned short u16x8 __attribute__((ext_vector_type(8)));

#define MFMA16(a, b, c) __builtin_amdgcn_mfma_f32_16x16x32_f16(a, b, c, 0, 0, 0)

__device__ __forceinline__ u16 f2h_u(float f) {
  union { f16 h; u16 u; } v; v.h = (f16)f; return v.u;
}
__device__ __forceinline__ float h2f(u16 u) {
  union { u16 u; f16 h; } v; v.u = u; return (float)v.h;
}
__device__ __forceinline__ f16x8 ld_h8(const u16* p) {
  return *(const f16x8*)p;
}
// async global->LDS, 16B per lane; LDS dest = wave-uniform base + lane*16
__device__ __forceinline__ void gl_lds16(const u16* g, u16* l) {
  __builtin_amdgcn_global_load_lds(
      (const __attribute__((address_space(1))) void*)g,
      (__attribute__((address_space(3))) void*)l, 16, 0, 0);
}

// ---------------------------------------------------------------------------
// f32 -> f16 elementwise convert (n8 = n/8 groups of 8)
// ---------------------------------------------------------------------------
__global__ __launch_bounds__(256) void convert_f32_f16(
    const float* __restrict__ in, u16* __restrict__ out, int n8)
{
  int i = blockIdx.x * 256 + threadIdx.x;
  int stride = gridDim.x * 256;
  for (; i < n8; i += stride) {
    f32x4 a = *(const f32x4*)(in + (size_t)i * 8);
    f32x4 b = *(const f32x4*)(in + (size_t)i * 8 + 4);
    u16x8 o;
#pragma unroll
    for (int j = 0; j < 4; ++j) { o[j] = f2h_u(a[j]); o[4 + j] = f2h_u(b[j]); }
    *(u16x8*)(out + (size_t)i * 8) = o;
  }
}

// ---------------------------------------------------------------------------
// f16-bits transpose (for V^T). Grid: (C/64, R/64, Z).
// ---------------------------------------------------------------------------
__global__ __launch_bounds__(256) void transpose_h16(
    const u16* __restrict__ in, u16* __restrict__ out,
    int R, int C, int ldi, int ldo, long zin, long zout)
{
  __shared__ u16 tile[64 * 66];
  const u16* ip = in + (size_t)blockIdx.z * zin;
  u16* op = out + (size_t)blockIdx.z * zout;
  int x0 = blockIdx.x * 64, y0 = blockIdx.y * 64;
  int t = threadIdx.x;
  int xr = (t & 15) * 4;
  int yr = t >> 4;
#pragma unroll
  for (int p = 0; p < 4; ++p) {
    int y = yr + p * 16;
    u16x4 v = *(const u16x4*)(ip + (size_t)(y0 + y) * ldi + x0 + xr);
    tile[y * 66 + xr + 0] = v.x;
    tile[y * 66 + xr + 1] = v.y;
    tile[y * 66 + xr + 2] = v.z;
    tile[y * 66 + xr + 3] = v.w;
  }
  __syncthreads();
#pragma unroll
  for (int p = 0; p < 4; ++p) {
    int x = (t >> 4) + p * 16;
    int yq = (t & 15) * 4;
    u16x4 v;
    v.x = tile[(yq + 0) * 66 + x];
    v.y = tile[(yq + 1) * 66 + x];
    v.z = tile[(yq + 2) * 66 + x];
    v.w = tile[(yq + 3) * 66 + x];
    *(u16x4*)(op + (size_t)(x0 + x) * ldo + y0 + yq) = v;
  }
}

// ---------------------------------------------------------------------------
// GEMM v6c (fused weight transpose): C[M][N] = A[M][K](f16) * W[K][N](f32).
// 256x128 tile, 8 waves, BK=32, 3 LDS buffers. A staged via gl_lds16
// (src-XOR-swizzled, depth-2); B reg-staged with ROTATED issue: BLOAD(t+2)
// happens at the END of iter t right after BWRITE(t+1) frees the single bw
// register set -> B gets a full iteration of latency cover with no extra
// VGPR (r13's depth-2-reg-sets spilled). Steady-state queue at the wait:
// [A(k+1) x2, B(k+1) x8, A(k+2) x2] -> vmcnt(2). bxfast=0 (by-fastest) for
// W-panel L2 reuse [r15 falsified bxfast=1]. Ktot clamps K for non-uniform
// split-K. Grid: (N/128, M/256, nz); partials at z*zstride.
// ---------------------------------------------------------------------------
template <bool F32OUT>
__global__ __launch_bounds__(512, 4) void gemm_ktn(
    const u16* __restrict__ A, const float* __restrict__ W, void* __restrict__ Cv,
    int Ksp, int Ktot, int bxfast, int lda, int ldw, int ldc, long zstride)
{
  __shared__ alignas(16) u16 As[3 * 256 * 32];   // 3 x 16 KB
  __shared__ alignas(16) u16 Bs[3 * 128 * 32];   // 3 x  8 KB
  int tid = threadIdx.x;
  int lane = tid & 63;
  int wave = tid >> 6;
  int wm = wave >> 2, wn = wave & 3;
  int r15 = lane & 15, g = lane >> 4;

  // XCD-bijective swizzle + supertile decomposition (bxfast selects order)
  int gx = gridDim.x, gy = gridDim.y;
  int nwg = gx * gy;
  int flat = blockIdx.y * gx + blockIdx.x;
  int q = nwg >> 3, rr = nwg & 7, xcd = flat & 7, lo = flat >> 3;
  int s = ((xcd < rr) ? xcd * (q + 1) : rr * (q + 1) + (xcd - rr) * q) + lo;
  int by, bx;
  if (bxfast) { bx = s % gx; by = s / gx; }
  else        { by = s % gy; bx = s / gy; }
  int row0 = by * 256, col0 = bx * 128;
  int kbeg = blockIdx.z * Ksp;
  int krem = Ktot - kbeg;
  int klen = (krem < Ksp) ? krem : Ksp;

  // A staging: lane covers LDS row tid>>2, 16B chunk tid&3, src XOR-swizzled
  int rA = tid >> 2;
  int pc = tid & 3;
  int cs = pc ^ ((rA >> 1) & 3);
  const u16* Ag0 = A + (size_t)(row0 + rA) * lda + kbeg + cs * 8;  // rows 0..127
  const u16* Ag1 = Ag0 + (size_t)128 * lda;                        // rows 128..255

  // B staging: col cB (coalesced across lanes), k-chunk kc (8 k each)
  int cB = tid & 127;
  int kc = tid >> 7;
  const float* Wg = W + (size_t)(kbeg + kc * 8) * ldw + col0 + cB;
  int bwoff = cB * 32 + ((kc ^ ((cB >> 1) & 3)) * 8);  // u16 units

  f32x4 acc[8][2];
#pragma unroll
  for (int i = 0; i < 8; ++i)
#pragma unroll
    for (int j = 0; j < 2; ++j) acc[i][j] = (f32x4){0.f, 0.f, 0.f, 0.f};

  int nk = klen >> 5;
  float bw[8];

  auto BLOAD = [&](int kk) {          // tile kk's 8 column f32 loads
#pragma unroll
    for (int j = 0; j < 8; ++j)
      bw[j] = Wg[(size_t)(kk * 32 + j) * ldw];
  };
  auto BWRITE = [&](int b) {          // convert + swizzled ds_write_b128
    u16x8 o;
#pragma unroll
    for (int j = 0; j < 8; ++j) o[j] = f2h_u(bw[j]);
    *(u16x8*)(Bs + b * 4096 + bwoff) = o;
  };
  auto STAGE_A = [&](int kk, int b) {
    u16* la = As + b * 8192 + wave * 512;
    gl_lds16(Ag0 + (size_t)kk * 32, la);
    gl_lds16(Ag1 + (size_t)kk * 32, la + 4096);
  };

  // prologue: B0 + A0 + A1 issued; vmcnt(2) confirms B0+A0 (A1 in flight);
  // BWRITE(0) frees bw; BLOAD(1) issues a full tile ahead.
  BLOAD(0);
  STAGE_A(0, 0);
  if (nk > 1) STAGE_A(1, 1);
  asm volatile("s_waitcnt vmcnt(2)" ::: "memory");
  BWRITE(0);
  if (nk > 1) BLOAD(1);
  asm volatile("s_waitcnt lgkmcnt(0)" ::: "memory");
  __builtin_amdgcn_s_barrier();

  int swz = (g ^ ((r15 >> 1) & 3)) * 8;
  int b0 = 0;
  for (int k = 0; k < nk; ++k) {
    const u16* Ab = As + b0 * 8192;
    const u16* Bb = Bs + b0 * 4096;
    // issue A prefetch for tile k+2 (overwrites (k-1)%3, barrier-protected)
    if (k + 2 < nk) {
      int b2 = b0 + 2; if (b2 >= 3) b2 -= 3;
      STAGE_A(k + 2, b2);
    }
    // frag reads for tile k (published by previous barrier)
    f16x8 bfr[2], af[4];
#pragma unroll
    for (int ni = 0; ni < 2; ++ni)
      bfr[ni] = ld_h8(Bb + (wn * 32 + ni * 16 + r15) * 32 + swz);
#pragma unroll
    for (int m2 = 0; m2 < 4; ++m2)
      af[m2] = ld_h8(Ab + (wm * 128 + m2 * 16 + r15) * 32 + swz);
    __builtin_amdgcn_s_setprio(1);
#pragma unroll
    for (int m2 = 0; m2 < 4; ++m2)
#pragma unroll
      for (int ni = 0; ni < 2; ++ni)
        acc[m2][ni] = MFMA16(af[m2], bfr[ni], acc[m2][ni]);
    f16x8 ag[4];
#pragma unroll
    for (int m2 = 0; m2 < 4; ++m2)
      ag[m2] = ld_h8(Ab + (wm * 128 + (4 + m2) * 16 + r15) * 32 + swz);
#pragma unroll
    for (int m2 = 0; m2 < 4; ++m2)
#pragma unroll
      for (int ni = 0; ni < 2; ++ni)
        acc[4 + m2][ni] = MFMA16(ag[m2], bfr[ni], acc[4 + m2][ni]);
    __builtin_amdgcn_s_setprio(0);
    // confirm A(k+1)+B(k+1) (B issued at END of iter k-1 -> full-iter cover);
    // leave A(k+2) in flight; BWRITE(k+1) then refill bw with B(k+2).
    if (k + 1 < nk) {
      if (k + 2 < nk) {
        asm volatile("s_waitcnt vmcnt(2)" ::: "memory");
      } else {
        asm volatile("s_waitcnt vmcnt(0)" ::: "memory");
      }
      int b1 = b0 + 1; if (b1 >= 3) b1 -= 3;
      BWRITE(b1);
      if (k + 2 < nk) BLOAD(k + 2);
    } else {
      asm volatile("s_waitcnt vmcnt(0)" ::: "memory");
    }
    asm volatile("s_waitcnt lgkmcnt(0)" ::: "memory");
    __builtin_amdgcn_s_barrier();   // publishes tile k+1 (A DMA + B ds_write)
    b0 = (b0 == 2) ? 0 : b0 + 1;
  }

  // C/D layout: col = lane&15, row = (lane>>4)*4 + reg
#pragma unroll
  for (int mi = 0; mi < 8; ++mi)
#pragma unroll
    for (int ni = 0; ni < 2; ++ni) {
      int row = row0 + wm * 128 + mi * 16 + g * 4;
      int col = col0 + wn * 32 + ni * 16 + r15;
#pragma unroll
      for (int r = 0; r < 4; ++r) {
        if constexpr (F32OUT)
          ((float*)Cv)[(size_t)blockIdx.z * zstride + (size_t)(row + r) * ldc + col] = acc[mi][ni][r];
        else
          ((u16*)Cv)[(size_t)blockIdx.z * zstride + (size_t)(row + r) * ldc + col] = f2h_u(acc[mi][ni][r]);
      }
    }
}

// ---------------------------------------------------------------------------
// out_f16[i] = sum of 8 f16 partial slices (n8 = n/8 groups of 8)
// ---------------------------------------------------------------------------
__global__ __launch_bounds__(256) void reduce_add8_h_f16(
    const u16* __restrict__ p, u16* __restrict__ out, int n8, long zs)
{
  int i = blockIdx.x * 256 + threadIdx.x;
  int stride = gridDim.x * 256;
  for (; i < n8; i += stride) {
    float s0[8] = {0.f, 0.f, 0.f, 0.f, 0.f, 0.f, 0.f, 0.f};
#pragma unroll
    for (int z = 0; z < 8; ++z) {
      u16x8 a = *(const u16x8*)(p + (size_t)z * zs + (size_t)i * 8);
#pragma unroll
      for (int j = 0; j < 8; ++j) s0[j] += h2f(a[j]);
    }
    u16x8 o;
#pragma unroll
    for (int j = 0; j < 8; ++j) o[j] = f2h_u(s0[j]);
    *(u16x8*)(out + (size_t)i * 8) = o;
  }
}

// ---------------------------------------------------------------------------
// out_f32[i] = sum of 3 f16 partial slices (n8 = n/8 groups of 8)
// ---------------------------------------------------------------------------
__global__ __launch_bounds__(256) void reduce_add3_h_f32(
    const u16* __restrict__ p, float* __restrict__ out, int n8, long zs)
{
  int i = blockIdx.x * 256 + threadIdx.x;
  int stride = gridDim.x * 256;
  for (; i < n8; i += stride) {
    u16x8 a0 = *(const u16x8*)(p + (size_t)i * 8);
    u16x8 a1 = *(const u16x8*)(p + zs + (size_t)i * 8);
    u16x8 a2 = *(const u16x8*)(p + 2 * zs + (size_t)i * 8);
    f32x4 o0, o1;
#pragma unroll
    for (int j = 0; j < 4; ++j) {
      o0[j] = h2f(a0[j]) + h2f(a1[j]) + h2f(a2[j]);
      o1[j] = h2f(a0[4 + j]) + h2f(a1[4 + j]) + h2f(a2[4 + j]);
    }
    *(f32x4*)(out + (size_t)i * 8) = o0;
    *(f32x4*)(out + (size_t)i * 8 + 4) = o1;
  }
}

// ---------------------------------------------------------------------------
// Per-(t, head) RMSNorm(*w) + RoPE for Q (f16 in place; w, freqs f32).
// ---------------------------------------------------------------------------
__global__ __launch_bounds__(64) void norm_rope_q(
    u16* __restrict__ q, const float* __restrict__ w,
    const float* __restrict__ fc, const float* __restrict__ fs)
{
  int t = blockIdx.x, h = blockIdx.y, lane = threadIdx.x;
  u16* row = q + (size_t)t * 16384 + h * 512;
  u16x8 v = *(const u16x8*)(row + lane * 8);
  float x[8];
  float ss = 0.f;
#pragma unroll
  for (int j = 0; j < 8; ++j) { x[j] = h2f(v[j]); ss += x[j] * x[j]; }
#pragma unroll
  for (int m = 1; m < 64; m <<= 1) ss += __shfl_xor(ss, m, 64);
  float rms = rsqrtf(ss * (1.f / 512.f) + 1e-6f);
  f32x4 w0 = *(const f32x4*)(w + lane * 8);
  f32x4 w1 = *(const f32x4*)(w + lane * 8 + 4);
  float y[8];
#pragma unroll
  for (int j = 0; j < 4; ++j) {
    y[j] = x[j] * rms * w0[j];
    y[4 + j] = x[4 + j] * rms * w1[j];
  }
  if (lane < 16) {
    f32x4 cv = *(const f32x4*)(fc + t * 64 + lane * 4);
    f32x4 sv = *(const f32x4*)(fs + t * 64 + lane * 4);
#pragma unroll
    for (int j = 0; j < 4; ++j) {
      float c = cv[j], s = sv[j];
      float a = y[2 * j], b = y[2 * j + 1];
      y[2 * j] = a * c - b * s;
      y[2 * j + 1] = a * s + b * c;
    }
  }
  u16x8 o;
#pragma unroll
  for (int j = 0; j < 8; ++j) o[j] = f2h_u(y[j]);
  *(u16x8*)(row + lane * 8) = o;
}

// ---------------------------------------------------------------------------
// Per-(t, kv): shared sumsq; k = rms*k_w + RoPE (in place), v = rms (-> vout).
// ---------------------------------------------------------------------------
__global__ __launch_bounds__(64) void norm_kv(
    u16* __restrict__ kraw, u16* __restrict__ vout, const float* __restrict__ kw,
    const float* __restrict__ fc, const float* __restrict__ fs)
{
  int t = blockIdx.x, kv = blockIdx.y, lane = threadIdx.x;
  u16* row  = kraw + (size_t)t * 2048 + kv * 512;
  u16* vrow = vout + (size_t)t * 2048 + kv * 512;
  u16x8 v = *(const u16x8*)(row + lane * 8);
  float x[8];
  float ss = 0.f;
#pragma unroll
  for (int j = 0; j < 8; ++j) { x[j] = h2f(v[j]); ss += x[j] * x[j]; }
#pragma unroll
  for (int m = 1; m < 64; m <<= 1) ss += __shfl_xor(ss, m, 64);
  float rms = rsqrtf(ss * (1.f / 512.f) + 1e-6f);
  f32x4 w0 = *(const f32x4*)(kw + lane * 8);
  f32x4 w1 = *(const f32x4*)(kw + lane * 8 + 4);
  float yk[8], yv[8];
#pragma unroll
  for (int j = 0; j < 4; ++j) {
    yv[j] = x[j] * rms;           yv[4 + j] = x[4 + j] * rms;
    yk[j] = yv[j] * w0[j];        yk[4 + j] = yv[4 + j] * w1[j];
  }
  if (lane < 16) {
    f32x4 cv = *(const f32x4*)(fc + t * 64 + lane * 4);
    f32x4 sv = *(const f32x4*)(fs + t * 64 + lane * 4);
#pragma unroll
    for (int j = 0; j < 4; ++j) {
      float c = cv[j], s = sv[j];
      float a = yk[2 * j], b = yk[2 * j + 1];
      yk[2 * j] = a * c - b * s;
      yk[2 * j + 1] = a * s + b * c;
    }
  }
  u16x8 ok, ov;
#pragma unroll
  for (int j = 0; j < 8; ++j) { ok[j] = f2h_u(yk[j]); ov[j] = f2h_u(yv[j]); }
  *(u16x8*)(row + lane * 8) = ok;
  *(u16x8*)(vrow + lane * 8) = ov;
}

// ---------------------------------------------------------------------------
// Flash attention v2: 4-wave block, 32 q-rows, D=512 split 4x128 across waves.
// ---------------------------------------------------------------------------
__global__ __launch_bounds__(256) void attn2_kernel(
    const u16* __restrict__ Q, const u16* __restrict__ Kb,
    const u16* __restrict__ Vt, u16* __restrict__ Y)
{
  __shared__ float Sred[4 * 32 * 68];
  __shared__ u16 Plds[32 * 64];
  __shared__ float scf[32];
  __shared__ float linv[32];
  __shared__ int nf[4];

  int h = blockIdx.x;
  int qtb = 31 - blockIdx.y;
  int kv = h >> 3;
  int tid = threadIdx.x;
  int lane = tid & 63;
  int w = tid >> 6;
  int r15 = lane & 15, g = lane >> 4;
  int qbase = qtb * 32;
  int dbase = w * 128;

  int jloc = lane >> 3, cl = lane & 7;
  int jrow = w * 8 + jloc;
  int qr_sm = qbase + jrow;

  f16x8 qf[2][4];
  {
    const u16* qp = Q + (size_t)(qbase + r15) * 16384 + h * 512 + dbase + g * 8;
#pragma unroll
    for (int mi = 0; mi < 2; ++mi)
#pragma unroll
      for (int ks = 0; ks < 4; ++ks)
        qf[mi][ks] = ld_h8(qp + (size_t)mi * 16 * 16384 + ks * 32);
  }

  f32x4 acc[2][8];
#pragma unroll
  for (int mi = 0; mi < 2; ++mi)
#pragma unroll
    for (int nt = 0; nt < 8; ++nt) acc[mi][nt] = (f32x4){0.f, 0.f, 0.f, 0.f};
  float m_ = -1e30f, l_ = 0.f;

  const u16* kp_base = Kb + kv * 512 + dbase;
  const u16* vt_base = Vt + (size_t)kv * (512 * 1024) + (size_t)dbase * 1024;
  int nst = (qbase + 31) / 64 + 1;

  for (int st = 0; st < nst; ++st) {
    int s0 = st * 64;
    f32x4 sa[2][4];
#pragma unroll
    for (int mi = 0; mi < 2; ++mi)
#pragma unroll
      for (int nt = 0; nt < 4; ++nt) sa[mi][nt] = (f32x4){0.f, 0.f, 0.f, 0.f};
#pragma unroll
    for (int ks = 0; ks < 4; ++ks) {
#pragma unroll
      for (int nt = 0; nt < 4; ++nt) {
        f16x8 kf = ld_h8(kp_base + (size_t)(s0 + nt * 16 + r15) * 2048 + ks * 32 + g * 8);
#pragma unroll
        for (int mi = 0; mi < 2; ++mi)
          sa[mi][nt] = MFMA16(qf[mi][ks], kf, sa[mi][nt]);
      }
    }
    {
      float* sw = Sred + w * 32 * 68;
#pragma unroll
      for (int mi = 0; mi < 2; ++mi)
#pragma unroll
        for (int nt = 0; nt < 4; ++nt)
#pragma unroll
          for (int r = 0; r < 4; ++r)
            sw[(mi * 16 + g * 4 + r) * 68 + nt * 16 + r15] = sa[mi][nt][r];
    }
    __syncthreads();

    {
      const float* sp = Sred + jrow * 68 + cl * 8;
      f32x4 a0 = *(const f32x4*)(sp);
      f32x4 a1 = *(const f32x4*)(sp + 4);
#pragma unroll
      for (int p = 1; p < 4; ++p) {
        a0 += *(const f32x4*)(sp + p * 32 * 68);
        a1 += *(const f32x4*)(sp + p * 32 * 68 + 4);
      }
      float sv[8];
      int sbase = s0 + cl * 8;
#pragma unroll
      for (int j = 0; j < 4; ++j) {
        sv[j]     = (sbase + j     <= qr_sm) ? a0[j] : -1e30f;
        sv[4 + j] = (sbase + 4 + j <= qr_sm) ? a1[j] : -1e30f;
      }
      float mm = sv[0];
#pragma unroll
      for (int j = 1; j < 8; ++j) mm = fmaxf(mm, sv[j]);
      mm = fmaxf(mm, __shfl_xor(mm, 1, 64));
      mm = fmaxf(mm, __shfl_xor(mm, 2, 64));
      mm = fmaxf(mm, __shfl_xor(mm, 4, 64));
      bool defer = (mm <= m_ + 8.f);
      float sc;
      if (defer) { sc = 1.f; }
      else { float mn = fmaxf(m_, mm); sc = __expf(m_ - mn); m_ = mn; }
      float pv8[8], rsum = 0.f;
#pragma unroll
      for (int j = 0; j < 8; ++j) { pv8[j] = __expf(sv[j] - m_); rsum += pv8[j]; }
      rsum += __shfl_xor(rsum, 1, 64);
      rsum += __shfl_xor(rsum, 2, 64);
      rsum += __shfl_xor(rsum, 4, 64);
      l_ = l_ * sc + rsum;
      u16x8 pw;
#pragma unroll
      for (int j = 0; j < 8; ++j) pw[j] = f2h_u(pv8[j]);
      *(u16x8*)(Plds + jrow * 64 + ((cl ^ (jrow & 7)) * 8)) = pw;
      if (cl == 0) scf[jrow] = sc;
      int need = __any((int)(!defer));
      if (lane == 0) nf[w] = need;
    }
    __syncthreads();

    if (nf[0] | nf[1] | nf[2] | nf[3]) {
#pragma unroll
      for (int mi = 0; mi < 2; ++mi)
#pragma unroll
        for (int r = 0; r < 4; ++r) {
          float s = scf[mi * 16 + g * 4 + r];
#pragma unroll
          for (int nt = 0; nt < 8; ++nt) acc[mi][nt][r] *= s;
        }
    }
    f16x8 pa[2][2];
#pragma unroll
    for (int mi = 0; mi < 2; ++mi)
#pragma unroll
      for (int ks = 0; ks < 2; ++ks) {
        int row = mi * 16 + r15;
        int c = ks * 4 + g;
        pa[mi][ks] = ld_h8(Plds + row * 64 + ((c ^ (row & 7)) * 8));
      }
#pragma unroll
    for (int ks = 0; ks < 2; ++ks)
#pragma unroll
      for (int nt = 0; nt < 8; ++nt) {
        f16x8 vf = ld_h8(vt_base + (size_t)(nt * 16 + r15) * 1024 + s0 + ks * 32 + g * 8);
#pragma unroll
        for (int mi = 0; mi < 2; ++mi)
          acc[mi][nt] = MFMA16(pa[mi][ks], vf, acc[mi][nt]);
      }
  }

  if (cl == 0) linv[jrow] = 1.0f / l_;
  __syncthreads();
#pragma unroll
  for (int mi = 0; mi < 2; ++mi)
#pragma unroll
    for (int r = 0; r < 4; ++r) {
      int row = mi * 16 + g * 4 + r;
      float li = linv[row];
      u16* yp = Y + (size_t)(qbase + row) * 16384 + h * 512 + dbase + r15;
#pragma unroll
      for (int nt = 0; nt < 8; ++nt)
        yp[nt * 16] = f2h_u(acc[mi][nt][r] * li);
    }
}

// ---------------------------------------------------------------------------
extern "C" void kernel_launch(void* const* d_in, const int* in_sizes, int n_in,
                              void* d_out, int out_size, void* d_ws, size_t ws_size,
                              hipStream_t stream)
{
  const float* x  = (const float*)d_in[0];
  const float* wq = (const float*)d_in[3];
  const float* wk = (const float*)d_in[4];
  const float* wo = (const float*)d_in[5];
  const float* qw = (const float*)d_in[6];
  const float* kw = (const float*)d_in[7];
  const float* fc = (const float*)d_in[10];
  const float* fs = (const float*)d_in[11];
  float* out = (float*)d_out;
  char* ws = (char*)d_ws;

  // ws layout (bytes):
  u16* Qbuf = (u16*)(ws + 0);            // [1024][16384] f16  32 MiB
  u16* Kbuf = (u16*)(ws + 33554432);     // [1024][2048]  f16   4 MiB
  u16* Vbuf = (u16*)(ws + 37748736);     // [1024][2048]  f16   4 MiB
  u16* Vt   = (u16*)(ws + 41943040);     // [4][512][1024] f16  4 MiB
  u16* Ybuf = (u16*)(ws + 46137344);     // [1024][16384] f16  32 MiB
  u16* xh   = (u16*)(ws + 79691776);     // [1024][5376]  f16  ~10.5 MiB
  // Split-K partials: wo uses Qbuf region (dead after attention) as 3x f16
  // slices; wk uses Ybuf region (dead until attention) as 8x f16 slices.
  u16* PbH  = (u16*)ws;                  // 3 x [1024][5376] f16 = 31.5 MiB
  u16* PbK  = (u16*)(ws + 46137344);     // 8 x [1024][2048] f16 = 32 MiB

  // 0) x -> f16
  convert_f32_f16<<<672, 256, 0, stream>>>(x, xh, (1024 * 5376) / 8);

  // 1) Q = x @ wq  (fused W-transpose GEMM, f16 out, by-fastest: W L2 reuse)
  gemm_ktn<false><<<dim3(128, 4, 1), 512, 0, stream>>>(
      xh, wq, (void*)Qbuf, 5376, 5376, 0, 5376, 16384, 16384, 0L);

  // 2) Kraw = x @ wk : split-K x8 (f16 partials into PbK), reduce -> Kbuf f16
  gemm_ktn<false><<<dim3(16, 4, 8), 512, 0, stream>>>(
      xh, wk, (void*)PbK, 672, 5376, 0, 5376, 2048, 2048, 2097152L);
  reduce_add8_h_f16<<<1024, 256, 0, stream>>>(PbK, Kbuf, 262144, 2097152L);

  // 3) norms + rope
  norm_rope_q<<<dim3(1024, 32), 64, 0, stream>>>(Qbuf, qw, fc, fs);
  norm_kv<<<dim3(1024, 4), 64, 0, stream>>>(Kbuf, Vbuf, kw, fc, fs);
  // 4) Vt[kv][d][t] = V^T
  transpose_h16<<<dim3(8, 16, 4), 256, 0, stream>>>(
      Vbuf, Vt, 1024, 512, 2048, 1024, 512L, 524288L);
  // 5) attention -> Ybuf [t][h*512+d]
  attn2_kernel<<<dim3(32, 32), 256, 0, stream>>>(Qbuf, Kbuf, Vt, Ybuf);

  // 6) out = Y @ wo : split-K x3 (f16 partials into PbH, non-uniform
  //    171/171/170 K-steps via Ktot clamp), reduce -> out f32
  gemm_ktn<false><<<dim3(42, 4, 3), 512, 0, stream>>>(
      Ybuf, wo, (void*)PbH, 5472, 16384, 0, 16384, 5376, 5376, 5505024L);
  reduce_add3_h_f32<<<2048, 256, 0, stream>>>(PbH, out, 688128, 5505024L);
}